// Round 10
// baseline (427.467 us; speedup 1.0000x reference)
//
#include <hip/hip_runtime.h>
#include <hip/hip_bf16.h>
#include <math.h>
#include <cstddef>

#define BSZ 2
#define DM 256
#define LSEQ 4096
#define DIN 512
#define DXZ 1024
#define DS 16
#define RANK 16
#define GXP 48
#define LC 32
#define NC 128   // LSEQ / LC
#define CSTRIDE (BSZ * DIN * 16)   // 16384 sequences
#define REPS 3   // instrumentation: x3 idempotent repeat to surface per-kernel time in rocprof top-5

typedef __attribute__((ext_vector_type(8))) short short8;
typedef __attribute__((ext_vector_type(4))) float f32x4;
struct bf4 { __hip_bfloat16 v[4]; };

__device__ __forceinline__ float silu_f(float x){ return x / (1.f + __expf(-x)); }
__device__ __forceinline__ float softplus_f(float x){ return fmaxf(x, 0.f) + log1pf(__expf(-fabsf(x))); }
__device__ __forceinline__ float b2f(__hip_bfloat16 v){ return __bfloat162float(v); }
__device__ __forceinline__ __hip_bfloat16 f2b(float v){ return __float2bfloat16(v); }

__device__ __forceinline__ void gl_lds16(const void* g, void* s){
    __builtin_amdgcn_global_load_lds((const __attribute__((address_space(1))) void*)g,
                                     (__attribute__((address_space(3))) void*)s, 16, 0, 0);
}

// ---------------- fused: LayerNorm-transpose (blocks 0-255) + weight cvt/pack (blocks 256-511) ----------------
__global__ __launch_bounds__(256) void k_pre(const float* __restrict__ x,
                                             const float* __restrict__ lnw, const float* __restrict__ lnb,
                                             const float* __restrict__ W_in, const float* __restrict__ W_xproj,
                                             const float* __restrict__ W_outp, const float* __restrict__ W_out,
                                             const float* __restrict__ W_skip, const float* __restrict__ b_out,
                                             const float* __restrict__ b_skip, const float* __restrict__ W_dt,
                                             const float* __restrict__ c1w, const float* __restrict__ c1b,
                                             const float* __restrict__ c2w, const float* __restrict__ c2b,
                                             const float* __restrict__ c3w, const float* __restrict__ c3b,
                                             __hip_bfloat16* __restrict__ xnb,
                                             __hip_bfloat16* __restrict__ Winb, __hip_bfloat16* __restrict__ Wxpb,
                                             __hip_bfloat16* __restrict__ Wopb, __hip_bfloat16* __restrict__ Wcb,
                                             __hip_bfloat16* __restrict__ Wdtb, float* __restrict__ bc,
                                             float* __restrict__ msw){
    __shared__ float tile[DM * 33];
    __shared__ float rsum[8][32], rsq[8][32];
    __shared__ float mu_s[32], rs_s[32];
    int tid = threadIdx.x;
    for (int rep = 0; rep < REPS; ++rep){
    __syncthreads();
    if (blockIdx.x < 256){
        int b  = blockIdx.x >> 7;
        int l0 = (blockIdx.x & 127) << 5;
        const float* xb = x + (size_t)b * DM * LSEQ;
        int lls = tid & 31, chi = tid >> 5;
        for (int cc = 0; cc < 32; ++cc){
            int c = cc * 8 + chi;
            tile[c * 33 + lls] = xb[(size_t)c * LSEQ + l0 + lls];
        }
        __syncthreads();
        int part = tid >> 5, l = tid & 31;
        float s = 0.f, sq = 0.f;
        for (int i = 0; i < 32; ++i){
            float v = tile[(part * 32 + i) * 33 + l];
            s += v; sq += v * v;
        }
        rsum[part][l] = s; rsq[part][l] = sq;
        __syncthreads();
        if (tid < 32){
            float ts = 0.f, tq = 0.f;
            for (int p = 0; p < 8; ++p){ ts += rsum[p][tid]; tq += rsq[p][tid]; }
            float mu  = ts * (1.f / DM);
            float var = tq * (1.f / DM) - mu * mu;
            mu_s[tid] = mu;
            rs_s[tid] = rsqrtf(var + 1e-5f);
        }
        __syncthreads();
        int c0 = tid & 63, lh = tid >> 6;
        for (int i = 0; i < 8; ++i){
            int ll = lh + 4 * i;
            float mu = mu_s[ll], rs = rs_s[ll];
            __hip_bfloat16* orow = xnb + (size_t)(b * LSEQ + l0 + ll) * 512;
            for (int j = 0; j < 4; ++j){
                int c = c0 + 64 * j;
                orow[c] = f2b((tile[c * 33 + ll] - mu) * rs * lnw[c] + lnb[c]);
            }
        }
    } else {
        int i0 = (blockIdx.x - 256) * 256 + tid;
        const int T = 256 * 256;
        for (int j = i0; j < 1024 * 256; j += T) Winb[j] = f2b(W_in[j]);
        for (int j = i0; j < 64 * 512; j += T){
            int r = j >> 9;
            Wxpb[j] = f2b(r < GXP ? W_xproj[r * 512 + (j & 511)] : 0.f);
        }
        for (int j = i0; j < 256 * 512; j += T) Wopb[j] = f2b(W_outp[j]);
        for (int j = i0; j < 256 * 512; j += T){
            int n = j >> 9, k = j & 511;
            Wcb[j] = f2b(k < 256 ? W_out[n * 256 + k] : W_skip[n * 256 + (k - 256)]);
        }
        for (int j = i0; j < 512 * 32; j += T){
            int n = j >> 5, k = j & 31;
            Wdtb[j] = f2b(k < 16 ? W_dt[n * 16 + k] : 0.f);
        }
        if (i0 < 256){
            bc[i0] = b_out[i0] + b_skip[i0];
            float* m = msw + i0 * 20;
            m[0] = c1w[i0*3]; m[1] = c1w[i0*3+1]; m[2] = c1w[i0*3+2];
            for (int j = 0; j < 5; ++j) m[3+j] = c2w[i0*5+j];
            for (int j = 0; j < 7; ++j) m[8+j] = c3w[i0*7+j];
            m[15] = c1b[i0]; m[16] = c2b[i0]; m[17] = c3b[i0];
            m[18] = 0.f; m[19] = 0.f;
        }
    }
    asm volatile("" ::: "memory");
    }
}

// ---------------- bf16 MFMA GEMM: C[M][ldc] = A[M][lda-strided] @ W[N][K]^T ----------------
// EPI: 1 = +bias, 8 = bf16 out, 16 = fused transpose+residual (xres), 32 = fused msconv epilogue
template<int EPI, int BM = 128, int BN = 64>
__global__ __launch_bounds__(256) void k_mgemm(const __hip_bfloat16* __restrict__ A, int lda,
                                               const __hip_bfloat16* __restrict__ W,
                                               const float* __restrict__ bias,
                                               void* __restrict__ Cv, int ldc,
                                               int N, int K,
                                               const float* __restrict__ xres = nullptr,
                                               const __hip_bfloat16* __restrict__ xnb2 = nullptr,
                                               const float* __restrict__ msw = nullptr){
    constexpr int SA  = BM / 8;
    constexpr int SAW = SA / 4;
    constexpr int SB  = BN / 8;
    constexpr int SBW = SB / 4;
    constexpr int WROWS = BM / 2;
    constexpr int WCOLS = BN / 2;
    constexpr int MI = WROWS / 16;
    constexpr int NI = WCOLS / 16;
    __shared__ __align__(16) __hip_bfloat16 As[BM * 64];
    __shared__ __align__(16) __hip_bfloat16 Ws[BN * 64];
    __shared__ float tileT[(EPI & 16) ? 64 * 65 : 1];
    const int tid = threadIdx.x;
    const int wave = tid >> 6, lane = tid & 63;
    const int brow = blockIdx.x * BM, bcol = blockIdx.y * BN;
    const int wm = wave >> 1, wn = wave & 1;

    const int a_row = lane >> 3;
    const int a_chk = lane & 7;
    const int a_scol = ((a_chk ^ a_row) * 8);

    const int lrow = lane & 15;
    const int kc = lane >> 4;
    const int r7 = lrow & 7;

    for (int rep = 0; rep < REPS; ++rep){
    __syncthreads();
    f32x4 acc[MI][NI] = {};

    for (int k0 = 0; k0 < K; k0 += 64){
#pragma unroll
        for (int j = 0; j < SAW; ++j){
            int seg = wave * SAW + j;
            const __hip_bfloat16* src = A + (size_t)(brow + seg * 8 + a_row) * lda + k0 + a_scol;
            gl_lds16(src, &As[seg * 512]);
        }
#pragma unroll
        for (int j = 0; j < SBW; ++j){
            int seg = wave * SBW + j;
            const __hip_bfloat16* src = W + (size_t)(bcol + seg * 8 + a_row) * K + k0 + a_scol;
            gl_lds16(src, &Ws[seg * 512]);
        }
        __syncthreads();
#pragma unroll
        for (int kk = 0; kk < 2; ++kk){
            int kchunk = kk * 4 + kc;
            short8 af[MI], bfr[NI];
#pragma unroll
            for (int mi = 0; mi < MI; ++mi){
                int row = wm * WROWS + mi * 16 + lrow;
                af[mi] = *(const short8*)&As[row * 64 + ((kchunk ^ r7) * 8)];
            }
#pragma unroll
            for (int ni = 0; ni < NI; ++ni){
                int row = wn * WCOLS + ni * 16 + lrow;
                bfr[ni] = *(const short8*)&Ws[row * 64 + ((kchunk ^ r7) * 8)];
            }
#pragma unroll
            for (int mi = 0; mi < MI; ++mi)
#pragma unroll
                for (int ni = 0; ni < NI; ++ni)
                    acc[mi][ni] = __builtin_amdgcn_mfma_f32_16x16x32_bf16(af[mi], bfr[ni], acc[mi][ni], 0, 0, 0);
        }
        __syncthreads();
    }

    if (EPI & 16){
#pragma unroll
        for (int ni = 0; ni < NI; ++ni){
            int nl = wn * WCOLS + ni * 16 + lrow;
#pragma unroll
            for (int mi = 0; mi < MI; ++mi){
                int ml = wm * WROWS + mi * 16 + kc * 4;
#pragma unroll
                for (int r = 0; r < 4; ++r)
                    tileT[nl * 65 + ml + r] = acc[mi][ni][r];
            }
        }
        __syncthreads();
        int b = brow >> 12, l0 = brow & 4095;
        int lr = tid & 63, nr = tid >> 6;
        float* out = (float*)Cv;
#pragma unroll
        for (int rr = 0; rr < 16; ++rr){
            int n = rr * 4 + nr;
            size_t o = (size_t)(b * DM + bcol + n) * LSEQ + l0 + lr;
            out[o] = tileT[n * 65 + lr] + bias[bcol + n] + xres[o];
        }
    } else if (EPI & 32){
#pragma unroll
        for (int ni = 0; ni < NI; ++ni){
            int n = bcol + wn * WCOLS + ni * 16 + lrow;
            float4 wv0 = *(const float4*)&msw[n * 20];
            float4 wv1 = *(const float4*)&msw[n * 20 + 4];
            float4 wv2 = *(const float4*)&msw[n * 20 + 8];
            float4 wv3 = *(const float4*)&msw[n * 20 + 12];
            float4 wv4 = *(const float4*)&msw[n * 20 + 16];
#pragma unroll
            for (int mi = 0; mi < MI; ++mi){
                int m0 = brow + wm * WROWS + mi * 16 + kc * 4;
                int l  = m0 & (LSEQ - 1);
                int bL = m0 - l;
                float v[10];
#pragma unroll
                for (int k = 0; k < 10; ++k){
                    int ll = l - 3 + k;
                    v[k] = ((unsigned)ll < LSEQ) ? b2f(xnb2[(size_t)(bL + ll) * 512 + n]) : 0.f;
                }
#pragma unroll
                for (int r = 0; r < 4; ++r){
                    float a1 = wv3.w + wv0.x * v[r+2] + wv0.y * v[r+3] + wv0.z * v[r+4];
                    float a2 = wv4.x + wv0.w * v[r+1] + wv1.x * v[r+2] + wv1.y * v[r+3]
                                     + wv1.z * v[r+4] + wv1.w * v[r+5];
                    float a3 = wv4.y + wv2.x * v[r] + wv2.y * v[r+1] + wv2.z * v[r+2]
                                     + wv2.w * v[r+3] + wv3.x * v[r+4] + wv3.y * v[r+5]
                                     + wv3.z * v[r+6];
                    float res = acc[mi][ni][r] + silu_f(a1) + silu_f(a2) + silu_f(a3);
                    ((__hip_bfloat16*)Cv)[(size_t)(m0 + r) * ldc + n] = f2b(res);
                }
            }
        }
    } else {
#pragma unroll
        for (int ni = 0; ni < NI; ++ni){
            int n = bcol + wn * WCOLS + ni * 16 + lrow;
            if (n >= N) continue;
            float bv = (EPI & 1) ? bias[n] : 0.f;
#pragma unroll
            for (int mi = 0; mi < MI; ++mi){
                int m0 = brow + wm * WROWS + mi * 16 + kc * 4;
#pragma unroll
                for (int r = 0; r < 4; ++r){
                    float v = acc[mi][ni][r] + bv;
                    if (EPI & 8) ((__hip_bfloat16*)Cv)[(size_t)(m0 + r) * ldc + n] = f2b(v);
                    else         ((float*)Cv)[(size_t)(m0 + r) * ldc + n] = v;
                }
            }
        }
    }
    asm volatile("" ::: "memory");
    }
}

// ---------------- fused xproj GEMM (32x64, K=512) + dt GEMM (K=16 via one MFMA) + softplus ----------------
__global__ __launch_bounds__(256) void k_xpdt(const __hip_bfloat16* __restrict__ A,
                                              const __hip_bfloat16* __restrict__ Wxp,
                                              const __hip_bfloat16* __restrict__ Wdt,
                                              const float* __restrict__ bdt,
                                              float* __restrict__ xdbl,
                                              __hip_bfloat16* __restrict__ delta){
    __shared__ __align__(16) __hip_bfloat16 As[32 * 64];
    __shared__ __align__(16) __hip_bfloat16 Ws[64 * 64];
    __shared__ __hip_bfloat16 xdl[32][34];
    const int tid = threadIdx.x, wave = tid >> 6, lane = tid & 63;
    const int brow = blockIdx.x * 32;
    const int wm = wave >> 1, wn = wave & 1;
    const int a_row = lane >> 3, a_chk = lane & 7, a_scol = ((a_chk ^ a_row) * 8);
    const int lrow = lane & 15, kc = lane >> 4, r7 = lrow & 7;

    for (int rep = 0; rep < REPS; ++rep){
    __syncthreads();
    for (int i = tid; i < 32 * 18; i += 256){
        int rr = i / 18, cc = 16 + i % 18;
        xdl[rr][cc] = f2b(0.f);
    }

    f32x4 acc[2] = {};
    for (int k0 = 0; k0 < 512; k0 += 64){
        {
            int seg = wave;
            gl_lds16(A + (size_t)(brow + seg * 8 + a_row) * 512 + k0 + a_scol, &As[seg * 512]);
        }
#pragma unroll
        for (int j = 0; j < 2; ++j){
            int seg = wave * 2 + j;
            gl_lds16(Wxp + (size_t)(seg * 8 + a_row) * 512 + k0 + a_scol, &Ws[seg * 512]);
        }
        __syncthreads();
#pragma unroll
        for (int kk = 0; kk < 2; ++kk){
            int kchunk = kk * 4 + kc;
            short8 af = *(const short8*)&As[(wm * 16 + lrow) * 64 + ((kchunk ^ r7) * 8)];
#pragma unroll
            for (int ni = 0; ni < 2; ++ni){
                short8 bfr = *(const short8*)&Ws[(wn * 32 + ni * 16 + lrow) * 64 + ((kchunk ^ r7) * 8)];
                acc[ni] = __builtin_amdgcn_mfma_f32_16x16x32_bf16(af, bfr, acc[ni], 0, 0, 0);
            }
        }
        __syncthreads();
    }

#pragma unroll
    for (int ni = 0; ni < 2; ++ni){
        int n = wn * 32 + ni * 16 + lrow;
        if (n < 48){
#pragma unroll
            for (int r = 0; r < 4; ++r){
                int ml = wm * 16 + kc * 4 + r;
                float fv = acc[ni][r];
                xdbl[(size_t)(brow + ml) * 48 + n] = fv;
                if (n < 16) xdl[ml][n] = f2b(fv);
            }
        }
    }
    __syncthreads();

#pragma unroll
    for (int ct8 = 0; ct8 < 8; ++ct8){
        int ct = wave * 8 + ct8;
        int n = ct * 16 + lrow;
        short8 bfr = *(const short8*)&Wdt[(size_t)n * 32 + kc * 8];
        float bv = bdt[n];
#pragma unroll
        for (int rt = 0; rt < 2; ++rt){
            short8 af = *(const short8*)&xdl[rt * 16 + lrow][kc * 8];
            f32x4 dacc = {};
            dacc = __builtin_amdgcn_mfma_f32_16x16x32_bf16(af, bfr, dacc, 0, 0, 0);
#pragma unroll
            for (int r = 0; r < 4; ++r){
                int m = brow + rt * 16 + kc * 4 + r;
                delta[(size_t)m * 512 + n] = f2b(softplus_f(dacc[r] + bv));
            }
        }
    }
    asm volatile("" ::: "memory");
    }
}

// ---------------- causal depthwise conv k=4 + SiLU (bf16 in/out, 4-wide) ----------------
__global__ __launch_bounds__(256) void k_conv(const __hip_bfloat16* __restrict__ xz,
                                              const float* __restrict__ cw,
                                              const float* __restrict__ cb,
                                              __hip_bfloat16* __restrict__ xc){
    int idx = blockIdx.x * 256 + threadIdx.x;
    int d4 = (idx & 127) * 4;
    int bl = idx >> 7;
    int l  = bl & (LSEQ - 1);
    for (int rep = 0; rep < REPS; ++rep){
    const __hip_bfloat16* base = xz + (size_t)bl * DXZ + d4;
    float4 bias = *(const float4*)(cb + d4);
    float acc[4] = {bias.x, bias.y, bias.z, bias.w};
    float4 w0 = *(const float4*)(cw + (d4 + 0) * 4);
    float4 w1 = *(const float4*)(cw + (d4 + 1) * 4);
    float4 w2 = *(const float4*)(cw + (d4 + 2) * 4);
    float4 w3 = *(const float4*)(cw + (d4 + 3) * 4);
    const float* wj[4] = {(const float*)&w0, (const float*)&w1, (const float*)&w2, (const float*)&w3};
#pragma unroll
    for (int t = 0; t < 4; ++t){
        int ls = l - (3 - t);
        if (ls >= 0){
            bf4 v = *(const bf4*)(base - (size_t)(3 - t) * DXZ);
#pragma unroll
            for (int j = 0; j < 4; ++j) acc[j] += wj[j][t] * b2f(v.v[j]);
        }
    }
    bf4 o;
#pragma unroll
    for (int j = 0; j < 4; ++j) o.v[j] = f2b(silu_f(acc[j]));
    *(bf4*)(xc + (size_t)bl * DIN + d4) = o;
    asm volatile("" ::: "memory");
    }
}

// ---------------- scan pass 1: per-chunk carries, n-split x2 ----------------
__global__ __launch_bounds__(512) void k_scan1(const __hip_bfloat16* __restrict__ delta,
                                               const __hip_bfloat16* __restrict__ xc,
                                               const float* __restrict__ xdbl,
                                               const float* __restrict__ A_log,
                                               float* __restrict__ Acar,
                                               float* __restrict__ Bcar){
    int bx = blockIdx.x;
    int dh = bx & 1;
    int c  = (bx >> 1) & (NC - 1);
    int b  = bx >> 8;
    int tid = threadIdx.x;
    int dloc = tid >> 1, nh = tid & 1;
    int d = dh * 256 + dloc;
    int n0 = nh * 8;
    __shared__ float Bs[LC][DS];
    for (int rep = 0; rep < REPS; ++rep){
    __syncthreads();
    {
        int t = tid >> 4, n = tid & 15;
        Bs[t][n] = xdbl[(size_t)(b * LSEQ + c * LC + t) * GXP + RANK + n];
    }
    __syncthreads();
    float Av[8];
    float a1 = -__expf(A_log[d * 16]);
    bool fast = true;
#pragma unroll
    for (int j = 0; j < 8; ++j){
        Av[j] = -__expf(A_log[d * 16 + n0 + j]);
        fast = fast && (fabsf(Av[j] - (float)(n0 + j + 1) * a1) <= 1e-4f * fabsf(Av[j]) + 1e-7f);
    }
    float ap[8], ac[8];
#pragma unroll
    for (int j = 0; j < 8; ++j){ ap[j] = 1.f; ac[j] = 0.f; }
    const __hip_bfloat16* dp = delta + (size_t)(b * LSEQ + c * LC) * DIN + d;
    const __hip_bfloat16* xp = xc    + (size_t)(b * LSEQ + c * LC) * DIN + d;
    if (fast){
        for (int t = 0; t < LC; ++t){
            float de = b2f(dp[(size_t)t * DIN]);
            float u  = de * b2f(xp[(size_t)t * DIN]);
            float p  = __expf(de * a1);
            float p2 = p * p, p4 = p2 * p2, p8 = p4 * p4;
            float da = nh ? p8 * p : p;
#pragma unroll
            for (int j = 0; j < 8; ++j){
                ap[j] *= da;
                ac[j] = da * ac[j] + u * Bs[t][n0 + j];
                da *= p;
            }
        }
    } else {
        for (int t = 0; t < LC; ++t){
            float de = b2f(dp[(size_t)t * DIN]);
            float u  = de * b2f(xp[(size_t)t * DIN]);
#pragma unroll
            for (int j = 0; j < 8; ++j){
                float da = __expf(de * Av[j]);
                ap[j] *= da;
                ac[j] = da * ac[j] + u * Bs[t][n0 + j];
            }
        }
    }
    size_t o = (size_t)c * CSTRIDE + (size_t)(b * DIN + d) * 16 + n0;
    *(float4*)(Acar + o)     = make_float4(ap[0], ap[1], ap[2], ap[3]);
    *(float4*)(Acar + o + 4) = make_float4(ap[4], ap[5], ap[6], ap[7]);
    *(float4*)(Bcar + o)     = make_float4(ac[0], ac[1], ac[2], ac[3]);
    *(float4*)(Bcar + o + 4) = make_float4(ac[4], ac[5], ac[6], ac[7]);
    asm volatile("" ::: "memory");
    }
}

// ---------------- scan pass 2: wave-parallel Kogge-Stone prefix over 128 chunks ----------------
__global__ __launch_bounds__(256) void k_scan2(const float* __restrict__ Acar,
                                               const float* __restrict__ Bcar,
                                               float* __restrict__ hinit){
    __shared__ float a_s[NC][33];
    __shared__ float b_s[NC][33];
    __shared__ float h_s[NC][33];
    const int tid = threadIdx.x;
    const int idx0 = blockIdx.x * 32;
    const int s_ld = tid & 31, cr = tid >> 5;
    for (int rep = 0; rep < REPS; ++rep){
    __syncthreads();
#pragma unroll
    for (int r = 0; r < 16; ++r){
        int c = r * 8 + cr;
        size_t g = (size_t)c * CSTRIDE + idx0 + s_ld;
        a_s[c][s_ld] = Acar[g];
        b_s[c][s_ld] = Bcar[g];
    }
    __syncthreads();
    const int lane = tid & 63, w = tid >> 6;
#pragma unroll
    for (int i = 0; i < 8; ++i){
        int s = w * 8 + i;
        float a0 = a_s[2 * lane][s],     b0 = b_s[2 * lane][s];
        float a1 = a_s[2 * lane + 1][s], b1 = b_s[2 * lane + 1][s];
        float av = a0 * a1, bv = a1 * b0 + b1;
#pragma unroll
        for (int d2 = 1; d2 < 64; d2 <<= 1){
            float ao = __shfl_up(av, d2);
            float bo = __shfl_up(bv, d2);
            if (lane >= d2){ bv = av * bo + bv; av = ao * av; }
        }
        float ax = __shfl_up(av, 1), bx = __shfl_up(bv, 1);
        if (lane == 0){ ax = 1.f; bx = 0.f; }
        h_s[2 * lane][s]     = bx;
        h_s[2 * lane + 1][s] = a0 * bx + b0;
    }
    __syncthreads();
#pragma unroll
    for (int r = 0; r < 16; ++r){
        int c = r * 8 + cr;
        hinit[(size_t)c * CSTRIDE + idx0 + s_ld] = h_s[c][s_ld];
    }
    asm volatile("" ::: "memory");
    }
}

// ---------------- scan pass 3: replay (n-split x2) + fused (y + D*xc)*silu(z), bf16 out ----------------
__global__ __launch_bounds__(512) void k_scan3(const __hip_bfloat16* __restrict__ delta,
                                               const __hip_bfloat16* __restrict__ xc,
                                               const __hip_bfloat16* __restrict__ xz,
                                               const float* __restrict__ xdbl,
                                               const float* __restrict__ A_log,
                                               const float* __restrict__ D_ssm,
                                               const float* __restrict__ hinit,
                                               __hip_bfloat16* __restrict__ y){
    int bx = blockIdx.x;
    int dh = bx & 1;
    int c  = (bx >> 1) & (NC - 1);
    int b  = bx >> 8;
    int tid = threadIdx.x;
    int dloc = tid >> 1, nh = tid & 1;
    int d = dh * 256 + dloc;
    int n0 = nh * 8;
    __shared__ float Bs[LC][DS], Cs[LC][DS];
    for (int rep = 0; rep < REPS; ++rep){
    __syncthreads();
    {
        int t = tid >> 4, n = tid & 15;
        size_t r = (size_t)(b * LSEQ + c * LC + t) * GXP;
        Bs[t][n] = xdbl[r + RANK + n];
        Cs[t][n] = xdbl[r + RANK + DS + n];
    }
    __syncthreads();
    float Av[8];
    float a1 = -__expf(A_log[d * 16]);
    bool fast = true;
#pragma unroll
    for (int j = 0; j < 8; ++j){
        Av[j] = -__expf(A_log[d * 16 + n0 + j]);
        fast = fast && (fabsf(Av[j] - (float)(n0 + j + 1) * a1) <= 1e-4f * fabsf(Av[j]) + 1e-7f);
    }
    float h[8];
    size_t ho = (size_t)c * CSTRIDE + (size_t)(b * DIN + d) * 16 + n0;
    {
        float4 h0 = *(const float4*)(hinit + ho);
        float4 h1 = *(const float4*)(hinit + ho + 4);
        h[0] = h0.x; h[1] = h0.y; h[2] = h0.z; h[3] = h0.w;
        h[4] = h1.x; h[5] = h1.y; h[6] = h1.z; h[7] = h1.w;
    }
    float Dd = D_ssm[d];
    size_t rb = (size_t)(b * LSEQ + c * LC);
    if (fast){
        for (int t = 0; t < LC; ++t){
            size_t row = rb + t;
            float de  = b2f(delta[row * DIN + d]);
            float xcv = b2f(xc[row * DIN + d]);
            float u = de * xcv;
            float p  = __expf(de * a1);
            float p2 = p * p, p4 = p2 * p2, p8 = p4 * p4;
            float da = nh ? p8 * p : p;
            float yv = 0.f;
#pragma unroll
            for (int j = 0; j < 8; ++j){
                h[j] = da * h[j] + u * Bs[t][n0 + j];
                yv += h[j] * Cs[t][n0 + j];
                da *= p;
            }
            yv += __shfl_xor(yv, 1);
            if (nh == 0){
                float zv = b2f(xz[row * DXZ + DIN + d]);
                y[row * DIN + d] = f2b((yv + Dd * xcv) * silu_f(zv));
            }
        }
    } else {
        for (int t = 0; t < LC; ++t){
            size_t row = rb + t;
            float de  = b2f(delta[row * DIN + d]);
            float xcv = b2f(xc[row * DIN + d]);
            float u = de * xcv;
            float yv = 0.f;
#pragma unroll
            for (int j = 0; j < 8; ++j){
                float da = __expf(de * Av[j]);
                h[j] = da * h[j] + u * Bs[t][n0 + j];
                yv += h[j] * Cs[t][n0 + j];
            }
            yv += __shfl_xor(yv, 1);
            if (nh == 0){
                float zv = b2f(xz[row * DXZ + DIN + d]);
                y[row * DIN + d] = f2b((yv + Dd * xcv) * silu_f(zv));
            }
        }
    }
    asm volatile("" ::: "memory");
    }
}

extern "C" void kernel_launch(void* const* d_in, const int* in_sizes, int n_in,
                              void* d_out, int out_size, void* d_ws, size_t ws_size,
                              hipStream_t stream){
    const float* x      = (const float*)d_in[0];
    const float* ln_w   = (const float*)d_in[1];
    const float* ln_b   = (const float*)d_in[2];
    const float* W_in   = (const float*)d_in[3];
    const float* conv_w = (const float*)d_in[4];
    const float* conv_b = (const float*)d_in[5];
    const float* W_xproj= (const float*)d_in[6];
    const float* W_dt   = (const float*)d_in[7];
    const float* b_dt   = (const float*)d_in[8];
    const float* A_log  = (const float*)d_in[9];
    const float* D_ssm  = (const float*)d_in[10];
    const float* W_outp = (const float*)d_in[11];
    const float* c1_w   = (const float*)d_in[12];
    const float* c1_b   = (const float*)d_in[13];
    const float* c2_w   = (const float*)d_in[14];
    const float* c2_b   = (const float*)d_in[15];
    const float* c3_w   = (const float*)d_in[16];
    const float* c3_b   = (const float*)d_in[17];
    const float* W_out  = (const float*)d_in[18];
    const float* b_out  = (const float*)d_in[19];
    const float* W_skip = (const float*)d_in[20];
    const float* b_skip = (const float*)d_in[21];
    float* out = (float*)d_out;

    char* base = (char*)d_ws;
    const size_t MB = 1024 * 1024;
    const size_t KB = 1024;
    __hip_bfloat16* Acomb = (__hip_bfloat16*)(base);            // [8192][512]  8 MB
    __hip_bfloat16* xzb   = (__hip_bfloat16*)(base + 8*MB);     // [8192][1024] 16 MB
    __hip_bfloat16* xcb   = (__hip_bfloat16*)(base + 24*MB);    // [8192][512]  8 MB
    float*          xdbl  = (float*)        (base + 32*MB);     // [8192][48]   1.5 MB
    __hip_bfloat16* deltab= (__hip_bfloat16*)(base + 34*MB);    // [8192][512]  8 MB
    float*          Acar  = (float*)        (base + 42*MB);     // 8 MB
    float*          Bcar  = (float*)        (base + 50*MB);     // 8 MB
    float*          hinit = (float*)        (base + 58*MB);     // 8 MB
    __hip_bfloat16* Winb  = (__hip_bfloat16*)(base + 66*MB);            // 512 KB
    __hip_bfloat16* Wxpb  = (__hip_bfloat16*)(base + 66*MB + 512*KB);   // 64 KB
    __hip_bfloat16* Wopb  = (__hip_bfloat16*)(base + 66*MB + 576*KB);   // 256 KB
    __hip_bfloat16* Wcb   = (__hip_bfloat16*)(base + 66*MB + 832*KB);   // 256 KB
    __hip_bfloat16* Wdtb  = (__hip_bfloat16*)(base + 66*MB + 1088*KB);  // 32 KB
    float*          bc    = (float*)        (base + 66*MB + 1120*KB);   // 4 KB
    float*          msw   = (float*)        (base + 66*MB + 1124*KB);   // 20 KB
    __hip_bfloat16* xnb   = Acomb + 256;                        // stride 512
    __hip_bfloat16* ybf   = (__hip_bfloat16*)Bcar;              // alias: Bcar dead after scan2

    const int M = BSZ * LSEQ;   // 8192

    k_pre<<<dim3(512), dim3(256), 0, stream>>>(x, ln_w, ln_b, W_in, W_xproj, W_outp, W_out, W_skip,
                                               b_out, b_skip, W_dt, c1_w, c1_b, c2_w, c2_b, c3_w, c3_b,
                                               xnb, Winb, Wxpb, Wopb, Wcb, Wdtb, bc, msw);
    k_mgemm<8, 128, 128><<<dim3(64, 8), dim3(256), 0, stream>>>(xnb, 512, Winb, nullptr, xzb, DXZ, 1024, 256);
    k_conv<<<dim3(M * DIN / 4 / 256), dim3(256), 0, stream>>>(xzb, conv_w, conv_b, xcb);
    k_xpdt<<<dim3(256), dim3(256), 0, stream>>>(xcb, Wxpb, Wdtb, b_dt, xdbl, deltab);
    k_scan1<<<dim3(BSZ * NC * 2), dim3(512), 0, stream>>>(deltab, xcb, xdbl, A_log, Acar, Bcar);
    k_scan2<<<dim3(512), dim3(256), 0, stream>>>(Acar, Bcar, hinit);
    k_scan3<<<dim3(BSZ * NC * 2), dim3(512), 0, stream>>>(deltab, xcb, xzb, xdbl, A_log, D_ssm, hinit, ybf);
    k_mgemm<32, 64, 64><<<dim3(128, 4), dim3(256), 0, stream>>>(ybf, 512, Wopb, nullptr, Acomb, 512, 256, 512,
                                                                nullptr, xnb, msw);
    k_mgemm<17, 64, 64><<<dim3(128, 4), dim3(256), 0, stream>>>(Acomb, 512, Wcb, bc, out, DM, 256, 512, x);
}

// Round 11
// 233.949 us; speedup vs baseline: 1.8272x; 1.8272x over previous
//
#include <hip/hip_runtime.h>
#include <hip/hip_bf16.h>
#include <math.h>
#include <cstddef>

#define BSZ 2
#define DM 256
#define LSEQ 4096
#define DIN 512
#define DXZ 1024
#define DS 16
#define RANK 16
#define GXP 48
#define LC 16
#define NC 256   // LSEQ / LC
#define CSTRIDE (BSZ * DIN * 16)   // 16384 sequences

typedef __attribute__((ext_vector_type(8))) short short8;
typedef __attribute__((ext_vector_type(4))) float f32x4;
struct bf4 { __hip_bfloat16 v[4]; };

__device__ __forceinline__ float silu_f(float x){ return x / (1.f + __expf(-x)); }
__device__ __forceinline__ float softplus_f(float x){ return fmaxf(x, 0.f) + log1pf(__expf(-fabsf(x))); }
__device__ __forceinline__ float b2f(__hip_bfloat16 v){ return __bfloat162float(v); }
__device__ __forceinline__ __hip_bfloat16 f2b(float v){ return __float2bfloat16(v); }

__device__ __forceinline__ void gl_lds16(const void* g, void* s){
    __builtin_amdgcn_global_load_lds((const __attribute__((address_space(1))) void*)g,
                                     (__attribute__((address_space(3))) void*)s, 16, 0, 0);
}

// ---------------- fused: LayerNorm-transpose (blocks 0-255) + weight cvt/pack (blocks 256-511) ----------------
__global__ __launch_bounds__(256) void k_pre(const float* __restrict__ x,
                                             const float* __restrict__ lnw, const float* __restrict__ lnb,
                                             const float* __restrict__ W_in, const float* __restrict__ W_xproj,
                                             const float* __restrict__ W_outp, const float* __restrict__ W_out,
                                             const float* __restrict__ W_skip, const float* __restrict__ b_out,
                                             const float* __restrict__ b_skip, const float* __restrict__ W_dt,
                                             const float* __restrict__ c1w, const float* __restrict__ c1b,
                                             const float* __restrict__ c2w, const float* __restrict__ c2b,
                                             const float* __restrict__ c3w, const float* __restrict__ c3b,
                                             __hip_bfloat16* __restrict__ xnb,
                                             __hip_bfloat16* __restrict__ Winb, __hip_bfloat16* __restrict__ Wxpb,
                                             __hip_bfloat16* __restrict__ Wopb, __hip_bfloat16* __restrict__ Wcb,
                                             __hip_bfloat16* __restrict__ Wdtb, float* __restrict__ bc,
                                             float* __restrict__ msw){
    __shared__ float tile[DM * 33];
    __shared__ float rsum[8][32], rsq[8][32];
    __shared__ float mu_s[32], rs_s[32];
    int tid = threadIdx.x;
    if (blockIdx.x < 256){
        int b  = blockIdx.x >> 7;
        int l0 = (blockIdx.x & 127) << 5;
        const float* xb = x + (size_t)b * DM * LSEQ;
        int lls = tid & 31, chi = tid >> 5;
        for (int cc = 0; cc < 32; ++cc){
            int c = cc * 8 + chi;
            tile[c * 33 + lls] = xb[(size_t)c * LSEQ + l0 + lls];
        }
        __syncthreads();
        int part = tid >> 5, l = tid & 31;
        float s = 0.f, sq = 0.f;
        for (int i = 0; i < 32; ++i){
            float v = tile[(part * 32 + i) * 33 + l];
            s += v; sq += v * v;
        }
        rsum[part][l] = s; rsq[part][l] = sq;
        __syncthreads();
        if (tid < 32){
            float ts = 0.f, tq = 0.f;
            for (int p = 0; p < 8; ++p){ ts += rsum[p][tid]; tq += rsq[p][tid]; }
            float mu  = ts * (1.f / DM);
            float var = tq * (1.f / DM) - mu * mu;
            mu_s[tid] = mu;
            rs_s[tid] = rsqrtf(var + 1e-5f);
        }
        __syncthreads();
        int c0 = tid & 63, lh = tid >> 6;
        for (int i = 0; i < 8; ++i){
            int ll = lh + 4 * i;
            float mu = mu_s[ll], rs = rs_s[ll];
            __hip_bfloat16* orow = xnb + (size_t)(b * LSEQ + l0 + ll) * 512;
            for (int j = 0; j < 4; ++j){
                int c = c0 + 64 * j;
                orow[c] = f2b((tile[c * 33 + ll] - mu) * rs * lnw[c] + lnb[c]);
            }
        }
    } else {
        int i0 = (blockIdx.x - 256) * 256 + tid;
        const int T = 256 * 256;
        for (int j = i0; j < 1024 * 256; j += T) Winb[j] = f2b(W_in[j]);
        for (int j = i0; j < 64 * 512; j += T){
            int r = j >> 9;
            Wxpb[j] = f2b(r < GXP ? W_xproj[r * 512 + (j & 511)] : 0.f);
        }
        for (int j = i0; j < 256 * 512; j += T) Wopb[j] = f2b(W_outp[j]);
        for (int j = i0; j < 256 * 512; j += T){
            int n = j >> 9, k = j & 511;
            Wcb[j] = f2b(k < 256 ? W_out[n * 256 + k] : W_skip[n * 256 + (k - 256)]);
        }
        for (int j = i0; j < 512 * 32; j += T){
            int n = j >> 5, k = j & 31;
            Wdtb[j] = f2b(k < 16 ? W_dt[n * 16 + k] : 0.f);
        }
        if (i0 < 256){
            bc[i0] = b_out[i0] + b_skip[i0];
            float* m = msw + i0 * 20;
            m[0] = c1w[i0*3]; m[1] = c1w[i0*3+1]; m[2] = c1w[i0*3+2];
            for (int j = 0; j < 5; ++j) m[3+j] = c2w[i0*5+j];
            for (int j = 0; j < 7; ++j) m[8+j] = c3w[i0*7+j];
            m[15] = c1b[i0]; m[16] = c2b[i0]; m[17] = c3b[i0];
            m[18] = 0.f; m[19] = 0.f;
        }
    }
}

// ---------------- bf16 MFMA GEMM: C[M][ldc] = A[M][lda-strided] @ W[N][K]^T ----------------
// EPI: 1 = +bias, 8 = bf16 out, 16 = fused transpose+residual (xres), 32 = fused msconv epilogue
template<int EPI, int BM = 128, int BN = 64>
__global__ __launch_bounds__(256) void k_mgemm(const __hip_bfloat16* __restrict__ A, int lda,
                                               const __hip_bfloat16* __restrict__ W,
                                               const float* __restrict__ bias,
                                               void* __restrict__ Cv, int ldc,
                                               int N, int K,
                                               const float* __restrict__ xres = nullptr,
                                               const __hip_bfloat16* __restrict__ xnb2 = nullptr,
                                               const float* __restrict__ msw = nullptr){
    constexpr int SA  = BM / 8;
    constexpr int SAW = SA / 4;
    constexpr int SB  = BN / 8;
    constexpr int SBW = SB / 4;
    constexpr int WROWS = BM / 2;
    constexpr int WCOLS = BN / 2;
    constexpr int MI = WROWS / 16;
    constexpr int NI = WCOLS / 16;
    __shared__ __align__(16) __hip_bfloat16 As[BM * 64];
    __shared__ __align__(16) __hip_bfloat16 Ws[BN * 64];
    __shared__ float tileT[(EPI & 16) ? 64 * 65 : 1];
    const int tid = threadIdx.x;
    const int wave = tid >> 6, lane = tid & 63;
    const int brow = blockIdx.x * BM, bcol = blockIdx.y * BN;
    const int wm = wave >> 1, wn = wave & 1;

    const int a_row = lane >> 3;
    const int a_chk = lane & 7;
    const int a_scol = ((a_chk ^ a_row) * 8);

    const int lrow = lane & 15;
    const int kc = lane >> 4;
    const int r7 = lrow & 7;

    f32x4 acc[MI][NI] = {};

    for (int k0 = 0; k0 < K; k0 += 64){
#pragma unroll
        for (int j = 0; j < SAW; ++j){
            int seg = wave * SAW + j;
            const __hip_bfloat16* src = A + (size_t)(brow + seg * 8 + a_row) * lda + k0 + a_scol;
            gl_lds16(src, &As[seg * 512]);
        }
#pragma unroll
        for (int j = 0; j < SBW; ++j){
            int seg = wave * SBW + j;
            const __hip_bfloat16* src = W + (size_t)(bcol + seg * 8 + a_row) * K + k0 + a_scol;
            gl_lds16(src, &Ws[seg * 512]);
        }
        __syncthreads();
#pragma unroll
        for (int kk = 0; kk < 2; ++kk){
            int kchunk = kk * 4 + kc;
            short8 af[MI], bfr[NI];
#pragma unroll
            for (int mi = 0; mi < MI; ++mi){
                int row = wm * WROWS + mi * 16 + lrow;
                af[mi] = *(const short8*)&As[row * 64 + ((kchunk ^ r7) * 8)];
            }
#pragma unroll
            for (int ni = 0; ni < NI; ++ni){
                int row = wn * WCOLS + ni * 16 + lrow;
                bfr[ni] = *(const short8*)&Ws[row * 64 + ((kchunk ^ r7) * 8)];
            }
#pragma unroll
            for (int mi = 0; mi < MI; ++mi)
#pragma unroll
                for (int ni = 0; ni < NI; ++ni)
                    acc[mi][ni] = __builtin_amdgcn_mfma_f32_16x16x32_bf16(af[mi], bfr[ni], acc[mi][ni], 0, 0, 0);
        }
        __syncthreads();
    }

    if (EPI & 16){
#pragma unroll
        for (int ni = 0; ni < NI; ++ni){
            int nl = wn * WCOLS + ni * 16 + lrow;
#pragma unroll
            for (int mi = 0; mi < MI; ++mi){
                int ml = wm * WROWS + mi * 16 + kc * 4;
#pragma unroll
                for (int r = 0; r < 4; ++r)
                    tileT[nl * 65 + ml + r] = acc[mi][ni][r];
            }
        }
        __syncthreads();
        int b = brow >> 12, l0 = brow & 4095;
        int lr = tid & 63, nr = tid >> 6;
        float* out = (float*)Cv;
#pragma unroll
        for (int rr = 0; rr < 16; ++rr){
            int n = rr * 4 + nr;
            size_t o = (size_t)(b * DM + bcol + n) * LSEQ + l0 + lr;
            out[o] = tileT[n * 65 + lr] + bias[bcol + n] + xres[o];
        }
        return;
    }

    if (EPI & 32){
#pragma unroll
        for (int ni = 0; ni < NI; ++ni){
            int n = bcol + wn * WCOLS + ni * 16 + lrow;
            float4 wv0 = *(const float4*)&msw[n * 20];
            float4 wv1 = *(const float4*)&msw[n * 20 + 4];
            float4 wv2 = *(const float4*)&msw[n * 20 + 8];
            float4 wv3 = *(const float4*)&msw[n * 20 + 12];
            float4 wv4 = *(const float4*)&msw[n * 20 + 16];
#pragma unroll
            for (int mi = 0; mi < MI; ++mi){
                int m0 = brow + wm * WROWS + mi * 16 + kc * 4;
                int l  = m0 & (LSEQ - 1);
                int bL = m0 - l;
                float v[10];
#pragma unroll
                for (int k = 0; k < 10; ++k){
                    int ll = l - 3 + k;
                    v[k] = ((unsigned)ll < LSEQ) ? b2f(xnb2[(size_t)(bL + ll) * 512 + n]) : 0.f;
                }
#pragma unroll
                for (int r = 0; r < 4; ++r){
                    float a1 = wv3.w + wv0.x * v[r+2] + wv0.y * v[r+3] + wv0.z * v[r+4];
                    float a2 = wv4.x + wv0.w * v[r+1] + wv1.x * v[r+2] + wv1.y * v[r+3]
                                     + wv1.z * v[r+4] + wv1.w * v[r+5];
                    float a3 = wv4.y + wv2.x * v[r] + wv2.y * v[r+1] + wv2.z * v[r+2]
                                     + wv2.w * v[r+3] + wv3.x * v[r+4] + wv3.y * v[r+5]
                                     + wv3.z * v[r+6];
                    float res = acc[mi][ni][r] + silu_f(a1) + silu_f(a2) + silu_f(a3);
                    ((__hip_bfloat16*)Cv)[(size_t)(m0 + r) * ldc + n] = f2b(res);
                }
            }
        }
        return;
    }

#pragma unroll
    for (int ni = 0; ni < NI; ++ni){
        int n = bcol + wn * WCOLS + ni * 16 + lrow;
        if (n >= N) continue;
        float bv = (EPI & 1) ? bias[n] : 0.f;
#pragma unroll
        for (int mi = 0; mi < MI; ++mi){
            int m0 = brow + wm * WROWS + mi * 16 + kc * 4;
#pragma unroll
            for (int r = 0; r < 4; ++r){
                float v = acc[mi][ni][r] + bv;
                if (EPI & 8) ((__hip_bfloat16*)Cv)[(size_t)(m0 + r) * ldc + n] = f2b(v);
                else         ((float*)Cv)[(size_t)(m0 + r) * ldc + n] = v;
            }
        }
    }
}

// ---------------- fused xproj GEMM (32x64, K=512) + dt GEMM (K=16 via one MFMA) + softplus ----------------
__global__ __launch_bounds__(256) void k_xpdt(const __hip_bfloat16* __restrict__ A,
                                              const __hip_bfloat16* __restrict__ Wxp,
                                              const __hip_bfloat16* __restrict__ Wdt,
                                              const float* __restrict__ bdt,
                                              float* __restrict__ xdbl,
                                              __hip_bfloat16* __restrict__ delta){
    __shared__ __align__(16) __hip_bfloat16 As[32 * 64];
    __shared__ __align__(16) __hip_bfloat16 Ws[64 * 64];
    __shared__ __hip_bfloat16 xdl[32][34];
    const int tid = threadIdx.x, wave = tid >> 6, lane = tid & 63;
    const int brow = blockIdx.x * 32;
    const int wm = wave >> 1, wn = wave & 1;
    const int a_row = lane >> 3, a_chk = lane & 7, a_scol = ((a_chk ^ a_row) * 8);
    const int lrow = lane & 15, kc = lane >> 4, r7 = lrow & 7;

    for (int i = tid; i < 32 * 18; i += 256){
        int rr = i / 18, cc = 16 + i % 18;
        xdl[rr][cc] = f2b(0.f);
    }

    f32x4 acc[2] = {};
    for (int k0 = 0; k0 < 512; k0 += 64){
        {
            int seg = wave;
            gl_lds16(A + (size_t)(brow + seg * 8 + a_row) * 512 + k0 + a_scol, &As[seg * 512]);
        }
#pragma unroll
        for (int j = 0; j < 2; ++j){
            int seg = wave * 2 + j;
            gl_lds16(Wxp + (size_t)(seg * 8 + a_row) * 512 + k0 + a_scol, &Ws[seg * 512]);
        }
        __syncthreads();
#pragma unroll
        for (int kk = 0; kk < 2; ++kk){
            int kchunk = kk * 4 + kc;
            short8 af = *(const short8*)&As[(wm * 16 + lrow) * 64 + ((kchunk ^ r7) * 8)];
#pragma unroll
            for (int ni = 0; ni < 2; ++ni){
                short8 bfr = *(const short8*)&Ws[(wn * 32 + ni * 16 + lrow) * 64 + ((kchunk ^ r7) * 8)];
                acc[ni] = __builtin_amdgcn_mfma_f32_16x16x32_bf16(af, bfr, acc[ni], 0, 0, 0);
            }
        }
        __syncthreads();
    }

#pragma unroll
    for (int ni = 0; ni < 2; ++ni){
        int n = wn * 32 + ni * 16 + lrow;
        if (n < 48){
#pragma unroll
            for (int r = 0; r < 4; ++r){
                int ml = wm * 16 + kc * 4 + r;
                float fv = acc[ni][r];
                xdbl[(size_t)(brow + ml) * 48 + n] = fv;
                if (n < 16) xdl[ml][n] = f2b(fv);
            }
        }
    }
    __syncthreads();

#pragma unroll
    for (int ct8 = 0; ct8 < 8; ++ct8){
        int ct = wave * 8 + ct8;
        int n = ct * 16 + lrow;
        short8 bfr = *(const short8*)&Wdt[(size_t)n * 32 + kc * 8];
        float bv = bdt[n];
#pragma unroll
        for (int rt = 0; rt < 2; ++rt){
            short8 af = *(const short8*)&xdl[rt * 16 + lrow][kc * 8];
            f32x4 dacc = {};
            dacc = __builtin_amdgcn_mfma_f32_16x16x32_bf16(af, bfr, dacc, 0, 0, 0);
#pragma unroll
            for (int r = 0; r < 4; ++r){
                int m = brow + rt * 16 + kc * 4 + r;
                delta[(size_t)m * 512 + n] = f2b(softplus_f(dacc[r] + bv));
            }
        }
    }
}

// ---------------- causal depthwise conv k=4 + SiLU (bf16 in/out, 4-wide) ----------------
__global__ __launch_bounds__(256) void k_conv(const __hip_bfloat16* __restrict__ xz,
                                              const float* __restrict__ cw,
                                              const float* __restrict__ cb,
                                              __hip_bfloat16* __restrict__ xc){
    int idx = blockIdx.x * 256 + threadIdx.x;
    int d4 = (idx & 127) * 4;
    int bl = idx >> 7;
    int l  = bl & (LSEQ - 1);
    const __hip_bfloat16* base = xz + (size_t)bl * DXZ + d4;
    float4 bias = *(const float4*)(cb + d4);
    float acc[4] = {bias.x, bias.y, bias.z, bias.w};
    float4 w0 = *(const float4*)(cw + (d4 + 0) * 4);
    float4 w1 = *(const float4*)(cw + (d4 + 1) * 4);
    float4 w2 = *(const float4*)(cw + (d4 + 2) * 4);
    float4 w3 = *(const float4*)(cw + (d4 + 3) * 4);
    const float* wj[4] = {(const float*)&w0, (const float*)&w1, (const float*)&w2, (const float*)&w3};
#pragma unroll
    for (int t = 0; t < 4; ++t){
        int ls = l - (3 - t);
        if (ls >= 0){
            bf4 v = *(const bf4*)(base - (size_t)(3 - t) * DXZ);
#pragma unroll
            for (int j = 0; j < 4; ++j) acc[j] += wj[j][t] * b2f(v.v[j]);
        }
    }
    bf4 o;
#pragma unroll
    for (int j = 0; j < 4; ++j) o.v[j] = f2b(silu_f(acc[j]));
    *(bf4*)(xc + (size_t)bl * DIN + d4) = o;
}

// ---------------- scan pass 1: per-chunk carries (LC=16), LDS-staged, power-tree inner ----------------
// grid 1024: [b(1b) | c(8b) | dh(1b)], 512 thr: dloc = tid>>1, nh = tid&1
__global__ __launch_bounds__(512) void k_scan1(const __hip_bfloat16* __restrict__ delta,
                                               const __hip_bfloat16* __restrict__ xc,
                                               const float* __restrict__ xdbl,
                                               const float* __restrict__ A_log,
                                               float* __restrict__ Acar,
                                               float* __restrict__ Bcar){
    int bx = blockIdx.x;
    int dh = bx & 1;
    int c  = (bx >> 1) & (NC - 1);
    int b  = bx >> 9;
    int tid = threadIdx.x;
    int dloc = tid >> 1, nh = tid & 1;
    int d = dh * 256 + dloc;
    int n0 = nh * 8;
    int rb = b * LSEQ + c * LC;
    __shared__ __align__(16) __hip_bfloat16 dl[LC][256];
    __shared__ __align__(16) __hip_bfloat16 xl[LC][256];
    __shared__ float Bs[LC][DS];
    const int w = tid >> 6, lane = tid & 63;
    {
        size_t rowg = (size_t)(rb + 2 * w + (lane >> 5));
        int col = (lane & 31) * 8;
        gl_lds16(delta + rowg * 512 + dh * 256 + col, &dl[2 * w][0]);
        gl_lds16(xc    + rowg * 512 + dh * 256 + col, &xl[2 * w][0]);
    }
    if (tid < 256){
        int t = tid >> 4, n = tid & 15;
        Bs[t][n] = xdbl[(size_t)(rb + t) * GXP + RANK + n];
    }
    __syncthreads();
    float Av[8];
    float a1 = -__expf(A_log[d * 16]);
    bool fast = true;
#pragma unroll
    for (int j = 0; j < 8; ++j){
        Av[j] = -__expf(A_log[d * 16 + n0 + j]);
        fast = fast && (fabsf(Av[j] - (float)(n0 + j + 1) * a1) <= 1e-4f * fabsf(Av[j]) + 1e-7f);
    }
    float ap[8], ac[8];
#pragma unroll
    for (int j = 0; j < 8; ++j){ ap[j] = 1.f; ac[j] = 0.f; }
    if (fast){
#pragma unroll 4
        for (int t = 0; t < LC; ++t){
            float de = b2f(dl[t][dloc]);
            float u  = de * b2f(xl[t][dloc]);
            float p  = __expf(de * a1);
            float p2 = p * p, p3 = p2 * p, p4 = p2 * p2;
            float qda[8] = {p, p2, p3, p4, p4 * p, p4 * p2, p4 * p3, p4 * p4};
            float bp = nh ? qda[7] : 1.f;
#pragma unroll
            for (int j = 0; j < 8; ++j){
                float da = qda[j] * bp;
                ap[j] *= da;
                ac[j] = da * ac[j] + u * Bs[t][n0 + j];
            }
        }
    } else {
        for (int t = 0; t < LC; ++t){
            float de = b2f(dl[t][dloc]);
            float u  = de * b2f(xl[t][dloc]);
#pragma unroll
            for (int j = 0; j < 8; ++j){
                float da = __expf(de * Av[j]);
                ap[j] *= da;
                ac[j] = da * ac[j] + u * Bs[t][n0 + j];
            }
        }
    }
    size_t o = (size_t)c * CSTRIDE + (size_t)(b * DIN + d) * 16 + n0;
    *(float4*)(Acar + o)     = make_float4(ap[0], ap[1], ap[2], ap[3]);
    *(float4*)(Acar + o + 4) = make_float4(ap[4], ap[5], ap[6], ap[7]);
    *(float4*)(Bcar + o)     = make_float4(ac[0], ac[1], ac[2], ac[3]);
    *(float4*)(Bcar + o + 4) = make_float4(ac[4], ac[5], ac[6], ac[7]);
}

// ---------------- scan pass 2: 256-chunk prefix; 16 seqs/block; 4 chunks/lane + Kogge-Stone ----------------
__global__ __launch_bounds__(256) void k_scan2(const float* __restrict__ Acar,
                                               const float* __restrict__ Bcar,
                                               float* __restrict__ hinit){
    __shared__ float a_s[16][257];
    __shared__ float b_s[16][257];
    const int tid = threadIdx.x;
    const int idx0 = blockIdx.x * 16;
    const int cs = tid >> 4, s_ld = tid & 15;
#pragma unroll
    for (int r = 0; r < 16; ++r){
        int c = r * 16 + cs;
        size_t g = (size_t)c * CSTRIDE + idx0 + s_ld;
        a_s[s_ld][c] = Acar[g];
        b_s[s_ld][c] = Bcar[g];
    }
    __syncthreads();
    const int lane = tid & 63, w = tid >> 6;
#pragma unroll
    for (int i = 0; i < 4; ++i){
        int s = w * 4 + i;
        float a4[4], b4[4];
#pragma unroll
        for (int k = 0; k < 4; ++k){ a4[k] = a_s[s][4 * lane + k]; b4[k] = b_s[s][4 * lane + k]; }
        float av = a4[0], bv = b4[0];
#pragma unroll
        for (int k = 1; k < 4; ++k){ bv = a4[k] * bv + b4[k]; av *= a4[k]; }
#pragma unroll
        for (int d2 = 1; d2 < 64; d2 <<= 1){
            float ao = __shfl_up(av, d2);
            float bo = __shfl_up(bv, d2);
            if (lane >= d2){ bv = av * bo + bv; av = ao * av; }
        }
        float bx = __shfl_up(bv, 1);
        if (lane == 0) bx = 0.f;
        float h = bx;
        b_s[s][4 * lane] = h;
#pragma unroll
        for (int k = 0; k < 3; ++k){ h = a4[k] * h + b4[k]; b_s[s][4 * lane + 1 + k] = h; }
    }
    __syncthreads();
#pragma unroll
    for (int r = 0; r < 16; ++r){
        int c = r * 16 + cs;
        hinit[(size_t)c * CSTRIDE + idx0 + s_ld] = b_s[s_ld][c];
    }
}

// ---------------- scan pass 3: replay (LC=16, staged) + fused (y + D*xc)*silu(z), coalesced y store ----------------
__global__ __launch_bounds__(512) void k_scan3(const __hip_bfloat16* __restrict__ delta,
                                               const __hip_bfloat16* __restrict__ xc,
                                               const __hip_bfloat16* __restrict__ xz,
                                               const float* __restrict__ xdbl,
                                               const float* __restrict__ A_log,
                                               const float* __restrict__ D_ssm,
                                               const float* __restrict__ hinit,
                                               __hip_bfloat16* __restrict__ y){
    int bx = blockIdx.x;
    int dh = bx & 1;
    int c  = (bx >> 1) & (NC - 1);
    int b  = bx >> 9;
    int tid = threadIdx.x;
    int dloc = tid >> 1, nh = tid & 1;
    int d = dh * 256 + dloc;
    int n0 = nh * 8;
    int rb = b * LSEQ + c * LC;
    __shared__ __align__(16) __hip_bfloat16 dl[LC][256];
    __shared__ __align__(16) __hip_bfloat16 xl[LC][256];
    __shared__ __align__(16) __hip_bfloat16 zl[LC][256];
    __shared__ float Bs[LC][DS], Cs[LC][DS];
    const int w = tid >> 6, lane = tid & 63;
    {
        size_t rowg = (size_t)(rb + 2 * w + (lane >> 5));
        int col = (lane & 31) * 8;
        gl_lds16(delta + rowg * 512 + dh * 256 + col, &dl[2 * w][0]);
        gl_lds16(xc    + rowg * 512 + dh * 256 + col, &xl[2 * w][0]);
        gl_lds16(xz    + rowg * 1024 + 512 + dh * 256 + col, &zl[2 * w][0]);
    }
    if (tid < 256){
        int t = tid >> 4, n = tid & 15;
        Bs[t][n] = xdbl[(size_t)(rb + t) * GXP + RANK + n];
    } else {
        int t = (tid >> 4) - 16, n = tid & 15;
        Cs[t][n] = xdbl[(size_t)(rb + t) * GXP + RANK + DS + n];
    }
    __syncthreads();
    float Av[8];
    float a1 = -__expf(A_log[d * 16]);
    bool fast = true;
#pragma unroll
    for (int j = 0; j < 8; ++j){
        Av[j] = -__expf(A_log[d * 16 + n0 + j]);
        fast = fast && (fabsf(Av[j] - (float)(n0 + j + 1) * a1) <= 1e-4f * fabsf(Av[j]) + 1e-7f);
    }
    float h[8];
    size_t ho = (size_t)c * CSTRIDE + (size_t)(b * DIN + d) * 16 + n0;
    {
        float4 h0 = *(const float4*)(hinit + ho);
        float4 h1 = *(const float4*)(hinit + ho + 4);
        h[0] = h0.x; h[1] = h0.y; h[2] = h0.z; h[3] = h0.w;
        h[4] = h1.x; h[5] = h1.y; h[6] = h1.z; h[7] = h1.w;
    }
    float Dd = D_ssm[d];
    if (fast){
#pragma unroll 4
        for (int t = 0; t < LC; ++t){
            float de  = b2f(dl[t][dloc]);
            float xcv = b2f(xl[t][dloc]);
            float u = de * xcv;
            float p  = __expf(de * a1);
            float p2 = p * p, p3 = p2 * p, p4 = p2 * p2;
            float qda[8] = {p, p2, p3, p4, p4 * p, p4 * p2, p4 * p3, p4 * p4};
            float bp = nh ? qda[7] : 1.f;
#pragma unroll
            for (int j = 0; j < 8; ++j)
                h[j] = (qda[j] * bp) * h[j] + u * Bs[t][n0 + j];
            float e0 = h[0] * Cs[t][n0]     + h[1] * Cs[t][n0 + 1];
            float e1 = h[2] * Cs[t][n0 + 2] + h[3] * Cs[t][n0 + 3];
            float e2 = h[4] * Cs[t][n0 + 4] + h[5] * Cs[t][n0 + 5];
            float e3 = h[6] * Cs[t][n0 + 6] + h[7] * Cs[t][n0 + 7];
            float yv = (e0 + e1) + (e2 + e3);
            yv += __shfl_xor(yv, 1);
            if (nh == 0){
                float zv = b2f(zl[t][dloc]);
                zl[t][dloc] = f2b((yv + Dd * xcv) * silu_f(zv));
            }
        }
    } else {
        for (int t = 0; t < LC; ++t){
            float de  = b2f(dl[t][dloc]);
            float xcv = b2f(xl[t][dloc]);
            float u = de * xcv;
            float yv = 0.f;
#pragma unroll
            for (int j = 0; j < 8; ++j){
                float da = __expf(de * Av[j]);
                h[j] = da * h[j] + u * Bs[t][n0 + j];
                yv += h[j] * Cs[t][n0 + j];
            }
            yv += __shfl_xor(yv, 1);
            if (nh == 0){
                float zv = b2f(zl[t][dloc]);
                zl[t][dloc] = f2b((yv + Dd * xcv) * silu_f(zv));
            }
        }
    }
    __syncthreads();
    // coalesced y store: 512 thr x 16 B covers the 16x256 bf16 tile
    {
        int row = tid >> 5, colv = (tid & 31) * 8;
        *(float4*)(y + (size_t)(rb + row) * 512 + dh * 256 + colv) = *(const float4*)(&zl[row][colv]);
    }
}

extern "C" void kernel_launch(void* const* d_in, const int* in_sizes, int n_in,
                              void* d_out, int out_size, void* d_ws, size_t ws_size,
                              hipStream_t stream){
    const float* x      = (const float*)d_in[0];
    const float* ln_w   = (const float*)d_in[1];
    const float* ln_b   = (const float*)d_in[2];
    const float* W_in   = (const float*)d_in[3];
    const float* conv_w = (const float*)d_in[4];
    const float* conv_b = (const float*)d_in[5];
    const float* W_xproj= (const float*)d_in[6];
    const float* W_dt   = (const float*)d_in[7];
    const float* b_dt   = (const float*)d_in[8];
    const float* A_log  = (const float*)d_in[9];
    const float* D_ssm  = (const float*)d_in[10];
    const float* W_outp = (const float*)d_in[11];
    const float* c1_w   = (const float*)d_in[12];
    const float* c1_b   = (const float*)d_in[13];
    const float* c2_w   = (const float*)d_in[14];
    const float* c2_b   = (const float*)d_in[15];
    const float* c3_w   = (const float*)d_in[16];
    const float* c3_b   = (const float*)d_in[17];
    const float* W_out  = (const float*)d_in[18];
    const float* b_out  = (const float*)d_in[19];
    const float* W_skip = (const float*)d_in[20];
    const float* b_skip = (const float*)d_in[21];
    float* out = (float*)d_out;

    char* base = (char*)d_ws;
    const size_t MB = 1024 * 1024;
    const size_t KB = 1024;
    __hip_bfloat16* Acomb = (__hip_bfloat16*)(base);            // [8192][512]  8 MB
    __hip_bfloat16* xzb   = (__hip_bfloat16*)(base + 8*MB);     // [8192][1024] 16 MB
    __hip_bfloat16* xcb   = (__hip_bfloat16*)(base + 24*MB);    // [8192][512]  8 MB
    float*          xdbl  = (float*)        (base + 32*MB);     // [8192][48]   1.5 MB
    __hip_bfloat16* deltab= (__hip_bfloat16*)(base + 34*MB);    // [8192][512]  8 MB
    float*          Acar  = (float*)        (base + 42*MB);     // 16 MB (NC=256)
    float*          Bcar  = (float*)        (base + 58*MB);     // 16 MB
    float*          hinit = (float*)        (base + 74*MB);     // 16 MB
    __hip_bfloat16* Winb  = (__hip_bfloat16*)(base + 90*MB);            // 512 KB
    __hip_bfloat16* Wxpb  = (__hip_bfloat16*)(base + 90*MB + 512*KB);   // 64 KB
    __hip_bfloat16* Wopb  = (__hip_bfloat16*)(base + 90*MB + 576*KB);   // 256 KB
    __hip_bfloat16* Wcb   = (__hip_bfloat16*)(base + 90*MB + 832*KB);   // 256 KB
    __hip_bfloat16* Wdtb  = (__hip_bfloat16*)(base + 90*MB + 1088*KB);  // 32 KB
    float*          bc    = (float*)        (base + 90*MB + 1120*KB);   // 4 KB
    float*          msw   = (float*)        (base + 90*MB + 1124*KB);   // 20 KB
    __hip_bfloat16* xnb   = Acomb + 256;                        // stride 512
    __hip_bfloat16* ybf   = (__hip_bfloat16*)Bcar;              // alias: Bcar dead after scan2

    const int M = BSZ * LSEQ;   // 8192

    k_pre<<<dim3(512), dim3(256), 0, stream>>>(x, ln_w, ln_b, W_in, W_xproj, W_outp, W_out, W_skip,
                                               b_out, b_skip, W_dt, c1_w, c1_b, c2_w, c2_b, c3_w, c3_b,
                                               xnb, Winb, Wxpb, Wopb, Wcb, Wdtb, bc, msw);
    k_mgemm<8, 128, 128><<<dim3(64, 8), dim3(256), 0, stream>>>(xnb, 512, Winb, nullptr, xzb, DXZ, 1024, 256);
    k_conv<<<dim3(M * DIN / 4 / 256), dim3(256), 0, stream>>>(xzb, conv_w, conv_b, xcb);
    k_xpdt<<<dim3(256), dim3(256), 0, stream>>>(xcb, Wxpb, Wdtb, b_dt, xdbl, deltab);
    k_scan1<<<dim3(BSZ * NC * 2), dim3(512), 0, stream>>>(deltab, xcb, xdbl, A_log, Acar, Bcar);
    k_scan2<<<dim3(1024), dim3(256), 0, stream>>>(Acar, Bcar, hinit);
    k_scan3<<<dim3(BSZ * NC * 2), dim3(512), 0, stream>>>(deltab, xcb, xzb, xdbl, A_log, D_ssm, hinit, ybf);
    k_mgemm<32, 64, 64><<<dim3(128, 4), dim3(256), 0, stream>>>(ybf, 512, Wopb, nullptr, Acomb, 512, 256, 512,
                                                                nullptr, xnb, msw);
    k_mgemm<17, 64, 64><<<dim3(128, 4), dim3(256), 0, stream>>>(Acomb, 512, Wcb, bc, out, DM, 256, 512, x);
}

// Round 12
// 229.285 us; speedup vs baseline: 1.8644x; 1.0203x over previous
//
#include <hip/hip_runtime.h>
#include <hip/hip_bf16.h>
#include <math.h>
#include <cstddef>

#define BSZ 2
#define DM 256
#define LSEQ 4096
#define DIN 512
#define DXZ 1024
#define DS 16
#define RANK 16
#define GXP 48
#define LC 16
#define NC 256   // LSEQ / LC
#define CSTRIDE (BSZ * DIN * 16)   // 16384 sequences

typedef __attribute__((ext_vector_type(8))) short short8;
typedef __attribute__((ext_vector_type(4))) float f32x4;
struct bf4 { __hip_bfloat16 v[4]; };

__device__ __forceinline__ float silu_f(float x){ return x / (1.f + __expf(-x)); }
__device__ __forceinline__ float softplus_f(float x){ return fmaxf(x, 0.f) + log1pf(__expf(-fabsf(x))); }
__device__ __forceinline__ float b2f(__hip_bfloat16 v){ return __bfloat162float(v); }
__device__ __forceinline__ __hip_bfloat16 f2b(float v){ return __float2bfloat16(v); }

__device__ __forceinline__ void gl_lds16(const void* g, void* s){
    __builtin_amdgcn_global_load_lds((const __attribute__((address_space(1))) void*)g,
                                     (__attribute__((address_space(3))) void*)s, 16, 0, 0);
}

// ---------------- fused: LayerNorm-transpose (blocks 0-255) + weight cvt/pack (blocks 256-511) ----------------
__global__ __launch_bounds__(256) void k_pre(const float* __restrict__ x,
                                             const float* __restrict__ lnw, const float* __restrict__ lnb,
                                             const float* __restrict__ W_in, const float* __restrict__ W_xproj,
                                             const float* __restrict__ W_outp, const float* __restrict__ W_out,
                                             const float* __restrict__ W_skip, const float* __restrict__ b_out,
                                             const float* __restrict__ b_skip, const float* __restrict__ W_dt,
                                             const float* __restrict__ c1w, const float* __restrict__ c1b,
                                             const float* __restrict__ c2w, const float* __restrict__ c2b,
                                             const float* __restrict__ c3w, const float* __restrict__ c3b,
                                             __hip_bfloat16* __restrict__ xnb,
                                             __hip_bfloat16* __restrict__ Winb, __hip_bfloat16* __restrict__ Wxpb,
                                             __hip_bfloat16* __restrict__ Wopb, __hip_bfloat16* __restrict__ Wcb,
                                             __hip_bfloat16* __restrict__ Wdtb, float* __restrict__ bc,
                                             float* __restrict__ msw){
    __shared__ float tile[DM * 33];
    __shared__ float rsum[8][32], rsq[8][32];
    __shared__ float mu_s[32], rs_s[32];
    int tid = threadIdx.x;
    if (blockIdx.x < 256){
        int b  = blockIdx.x >> 7;
        int l0 = (blockIdx.x & 127) << 5;
        const float* xb = x + (size_t)b * DM * LSEQ;
        int lls = tid & 31, chi = tid >> 5;
        for (int cc = 0; cc < 32; ++cc){
            int c = cc * 8 + chi;
            tile[c * 33 + lls] = xb[(size_t)c * LSEQ + l0 + lls];
        }
        __syncthreads();
        int part = tid >> 5, l = tid & 31;
        float s = 0.f, sq = 0.f;
        for (int i = 0; i < 32; ++i){
            float v = tile[(part * 32 + i) * 33 + l];
            s += v; sq += v * v;
        }
        rsum[part][l] = s; rsq[part][l] = sq;
        __syncthreads();
        if (tid < 32){
            float ts = 0.f, tq = 0.f;
            for (int p = 0; p < 8; ++p){ ts += rsum[p][tid]; tq += rsq[p][tid]; }
            float mu  = ts * (1.f / DM);
            float var = tq * (1.f / DM) - mu * mu;
            mu_s[tid] = mu;
            rs_s[tid] = rsqrtf(var + 1e-5f);
        }
        __syncthreads();
        int c0 = tid & 63, lh = tid >> 6;
        for (int i = 0; i < 8; ++i){
            int ll = lh + 4 * i;
            float mu = mu_s[ll], rs = rs_s[ll];
            __hip_bfloat16* orow = xnb + (size_t)(b * LSEQ + l0 + ll) * 512;
            for (int j = 0; j < 4; ++j){
                int c = c0 + 64 * j;
                orow[c] = f2b((tile[c * 33 + ll] - mu) * rs * lnw[c] + lnb[c]);
            }
        }
    } else {
        int i0 = (blockIdx.x - 256) * 256 + tid;
        const int T = 256 * 256;
        for (int j = i0; j < 1024 * 256; j += T) Winb[j] = f2b(W_in[j]);
        for (int j = i0; j < 64 * 512; j += T){
            int r = j >> 9;
            Wxpb[j] = f2b(r < GXP ? W_xproj[r * 512 + (j & 511)] : 0.f);
        }
        for (int j = i0; j < 256 * 512; j += T) Wopb[j] = f2b(W_outp[j]);
        for (int j = i0; j < 256 * 512; j += T){
            int n = j >> 9, k = j & 511;
            Wcb[j] = f2b(k < 256 ? W_out[n * 256 + k] : W_skip[n * 256 + (k - 256)]);
        }
        for (int j = i0; j < 512 * 32; j += T){
            int n = j >> 5, k = j & 31;
            Wdtb[j] = f2b(k < 16 ? W_dt[n * 16 + k] : 0.f);
        }
        if (i0 < 256){
            bc[i0] = b_out[i0] + b_skip[i0];
            float* m = msw + i0 * 20;
            m[0] = c1w[i0*3]; m[1] = c1w[i0*3+1]; m[2] = c1w[i0*3+2];
            for (int j = 0; j < 5; ++j) m[3+j] = c2w[i0*5+j];
            for (int j = 0; j < 7; ++j) m[8+j] = c3w[i0*7+j];
            m[15] = c1b[i0]; m[16] = c2b[i0]; m[17] = c3b[i0];
            m[18] = 0.f; m[19] = 0.f;
        }
    }
}

// ---------------- bf16 MFMA GEMM: C[M][ldc] = A[M][lda-strided] @ W[N][K]^T ----------------
// EPI: 1 = +bias, 8 = bf16 out, 16 = fused transpose+residual (xres), 32 = fused msconv epilogue
template<int EPI, int BM = 128, int BN = 64>
__global__ __launch_bounds__(256) void k_mgemm(const __hip_bfloat16* __restrict__ A, int lda,
                                               const __hip_bfloat16* __restrict__ W,
                                               const float* __restrict__ bias,
                                               void* __restrict__ Cv, int ldc,
                                               int N, int K,
                                               const float* __restrict__ xres = nullptr,
                                               const __hip_bfloat16* __restrict__ xnb2 = nullptr,
                                               const float* __restrict__ msw = nullptr){
    constexpr int SA  = BM / 8;
    constexpr int SAW = SA / 4;
    constexpr int SB  = BN / 8;
    constexpr int SBW = SB / 4;
    constexpr int WROWS = BM / 2;
    constexpr int WCOLS = BN / 2;
    constexpr int MI = WROWS / 16;
    constexpr int NI = WCOLS / 16;
    __shared__ __align__(16) __hip_bfloat16 As[BM * 64];
    __shared__ __align__(16) __hip_bfloat16 Ws[BN * 64];
    __shared__ float tileT[(EPI & 16) ? 64 * 65 : 1];
    const int tid = threadIdx.x;
    const int wave = tid >> 6, lane = tid & 63;
    const int brow = blockIdx.x * BM, bcol = blockIdx.y * BN;
    const int wm = wave >> 1, wn = wave & 1;

    const int a_row = lane >> 3;
    const int a_chk = lane & 7;
    const int a_scol = ((a_chk ^ a_row) * 8);

    const int lrow = lane & 15;
    const int kc = lane >> 4;
    const int r7 = lrow & 7;

    f32x4 acc[MI][NI] = {};

    for (int k0 = 0; k0 < K; k0 += 64){
#pragma unroll
        for (int j = 0; j < SAW; ++j){
            int seg = wave * SAW + j;
            const __hip_bfloat16* src = A + (size_t)(brow + seg * 8 + a_row) * lda + k0 + a_scol;
            gl_lds16(src, &As[seg * 512]);
        }
#pragma unroll
        for (int j = 0; j < SBW; ++j){
            int seg = wave * SBW + j;
            const __hip_bfloat16* src = W + (size_t)(bcol + seg * 8 + a_row) * K + k0 + a_scol;
            gl_lds16(src, &Ws[seg * 512]);
        }
        __syncthreads();
#pragma unroll
        for (int kk = 0; kk < 2; ++kk){
            int kchunk = kk * 4 + kc;
            short8 af[MI], bfr[NI];
#pragma unroll
            for (int mi = 0; mi < MI; ++mi){
                int row = wm * WROWS + mi * 16 + lrow;
                af[mi] = *(const short8*)&As[row * 64 + ((kchunk ^ r7) * 8)];
            }
#pragma unroll
            for (int ni = 0; ni < NI; ++ni){
                int row = wn * WCOLS + ni * 16 + lrow;
                bfr[ni] = *(const short8*)&Ws[row * 64 + ((kchunk ^ r7) * 8)];
            }
#pragma unroll
            for (int mi = 0; mi < MI; ++mi)
#pragma unroll
                for (int ni = 0; ni < NI; ++ni)
                    acc[mi][ni] = __builtin_amdgcn_mfma_f32_16x16x32_bf16(af[mi], bfr[ni], acc[mi][ni], 0, 0, 0);
        }
        __syncthreads();
    }

    if (EPI & 16){
#pragma unroll
        for (int ni = 0; ni < NI; ++ni){
            int nl = wn * WCOLS + ni * 16 + lrow;
#pragma unroll
            for (int mi = 0; mi < MI; ++mi){
                int ml = wm * WROWS + mi * 16 + kc * 4;
#pragma unroll
                for (int r = 0; r < 4; ++r)
                    tileT[nl * 65 + ml + r] = acc[mi][ni][r];
            }
        }
        __syncthreads();
        int b = brow >> 12, l0 = brow & 4095;
        int lr = tid & 63, nr = tid >> 6;
        float* out = (float*)Cv;
#pragma unroll
        for (int rr = 0; rr < 16; ++rr){
            int n = rr * 4 + nr;
            size_t o = (size_t)(b * DM + bcol + n) * LSEQ + l0 + lr;
            out[o] = tileT[n * 65 + lr] + bias[bcol + n] + xres[o];
        }
        return;
    }

    if (EPI & 32){
#pragma unroll
        for (int ni = 0; ni < NI; ++ni){
            int n = bcol + wn * WCOLS + ni * 16 + lrow;
            float4 wv0 = *(const float4*)&msw[n * 20];
            float4 wv1 = *(const float4*)&msw[n * 20 + 4];
            float4 wv2 = *(const float4*)&msw[n * 20 + 8];
            float4 wv3 = *(const float4*)&msw[n * 20 + 12];
            float4 wv4 = *(const float4*)&msw[n * 20 + 16];
#pragma unroll
            for (int mi = 0; mi < MI; ++mi){
                int m0 = brow + wm * WROWS + mi * 16 + kc * 4;
                int l  = m0 & (LSEQ - 1);
                int bL = m0 - l;
                float v[10];
#pragma unroll
                for (int k = 0; k < 10; ++k){
                    int ll = l - 3 + k;
                    v[k] = ((unsigned)ll < LSEQ) ? b2f(xnb2[(size_t)(bL + ll) * 512 + n]) : 0.f;
                }
#pragma unroll
                for (int r = 0; r < 4; ++r){
                    float a1 = wv3.w + wv0.x * v[r+2] + wv0.y * v[r+3] + wv0.z * v[r+4];
                    float a2 = wv4.x + wv0.w * v[r+1] + wv1.x * v[r+2] + wv1.y * v[r+3]
                                     + wv1.z * v[r+4] + wv1.w * v[r+5];
                    float a3 = wv4.y + wv2.x * v[r] + wv2.y * v[r+1] + wv2.z * v[r+2]
                                     + wv2.w * v[r+3] + wv3.x * v[r+4] + wv3.y * v[r+5]
                                     + wv3.z * v[r+6];
                    float res = acc[mi][ni][r] + silu_f(a1) + silu_f(a2) + silu_f(a3);
                    ((__hip_bfloat16*)Cv)[(size_t)(m0 + r) * ldc + n] = f2b(res);
                }
            }
        }
        return;
    }

#pragma unroll
    for (int ni = 0; ni < NI; ++ni){
        int n = bcol + wn * WCOLS + ni * 16 + lrow;
        if (n >= N) continue;
        float bv = (EPI & 1) ? bias[n] : 0.f;
#pragma unroll
        for (int mi = 0; mi < MI; ++mi){
            int m0 = brow + wm * WROWS + mi * 16 + kc * 4;
#pragma unroll
            for (int r = 0; r < 4; ++r){
                float v = acc[mi][ni][r] + bv;
                if (EPI & 8) ((__hip_bfloat16*)Cv)[(size_t)(m0 + r) * ldc + n] = f2b(v);
                else         ((float*)Cv)[(size_t)(m0 + r) * ldc + n] = v;
            }
        }
    }
}

// ---------------- fused xproj GEMM + dt GEMM + softplus + SCAN-1 CARRIES (bf16 out) ----------------
// Block handles rows brow..brow+31 = chunks c0, c0+1 (LC=16).  1 block/CU.
__global__ __launch_bounds__(256) void k_xpdt(const __hip_bfloat16* __restrict__ A,    // xcb
                                              const __hip_bfloat16* __restrict__ Wxp,
                                              const __hip_bfloat16* __restrict__ Wdt,
                                              const float* __restrict__ bdt,
                                              const float* __restrict__ A_log,
                                              float* __restrict__ xdbl,
                                              __hip_bfloat16* __restrict__ delta,
                                              __hip_bfloat16* __restrict__ Acar,
                                              __hip_bfloat16* __restrict__ Bcar){
    __shared__ __align__(16) __hip_bfloat16 As[32 * 64];
    __shared__ __align__(16) __hip_bfloat16 Ws[64 * 64];
    __shared__ __hip_bfloat16 xdl[32][34];
    __shared__ __hip_bfloat16 dls[32][520];   // delta staged (pad 8 -> 2-way banks)
    __shared__ float Bls[32][16];             // B columns staged
    const int tid = threadIdx.x, wave = tid >> 6, lane = tid & 63;
    const int brow = blockIdx.x * 32;
    const int wm = wave >> 1, wn = wave & 1;
    const int a_row = lane >> 3, a_chk = lane & 7, a_scol = ((a_chk ^ a_row) * 8);
    const int lrow = lane & 15, kc = lane >> 4, r7 = lrow & 7;

    for (int i = tid; i < 32 * 18; i += 256){
        int rr = i / 18, cc = 16 + i % 18;
        xdl[rr][cc] = f2b(0.f);
    }

    f32x4 acc[2] = {};
    for (int k0 = 0; k0 < 512; k0 += 64){
        {
            int seg = wave;
            gl_lds16(A + (size_t)(brow + seg * 8 + a_row) * 512 + k0 + a_scol, &As[seg * 512]);
        }
#pragma unroll
        for (int j = 0; j < 2; ++j){
            int seg = wave * 2 + j;
            gl_lds16(Wxp + (size_t)(seg * 8 + a_row) * 512 + k0 + a_scol, &Ws[seg * 512]);
        }
        __syncthreads();
#pragma unroll
        for (int kk = 0; kk < 2; ++kk){
            int kchunk = kk * 4 + kc;
            short8 af = *(const short8*)&As[(wm * 16 + lrow) * 64 + ((kchunk ^ r7) * 8)];
#pragma unroll
            for (int ni = 0; ni < 2; ++ni){
                short8 bfr = *(const short8*)&Ws[(wn * 32 + ni * 16 + lrow) * 64 + ((kchunk ^ r7) * 8)];
                acc[ni] = __builtin_amdgcn_mfma_f32_16x16x32_bf16(af, bfr, acc[ni], 0, 0, 0);
            }
        }
        __syncthreads();
    }

    // write xdbl (f32, n<48); stage dt-inputs (n<16) and B (16<=n<32) to LDS
#pragma unroll
    for (int ni = 0; ni < 2; ++ni){
        int n = wn * 32 + ni * 16 + lrow;
        if (n < 48){
#pragma unroll
            for (int r = 0; r < 4; ++r){
                int ml = wm * 16 + kc * 4 + r;
                float fv = acc[ni][r];
                xdbl[(size_t)(brow + ml) * 48 + n] = fv;
                if (n < 16) xdl[ml][n] = f2b(fv);
                else if (n < 32) Bls[ml][n - 16] = fv;
            }
        }
    }
    __syncthreads();

    // dt: delta = softplus(xdl @ Wdt^T + bdt); write global + stage to dls
#pragma unroll
    for (int ct8 = 0; ct8 < 8; ++ct8){
        int ct = wave * 8 + ct8;
        int n = ct * 16 + lrow;
        short8 bfr = *(const short8*)&Wdt[(size_t)n * 32 + kc * 8];
        float bv = bdt[n];
#pragma unroll
        for (int rt = 0; rt < 2; ++rt){
            short8 af = *(const short8*)&xdl[rt * 16 + lrow][kc * 8];
            f32x4 dacc = {};
            dacc = __builtin_amdgcn_mfma_f32_16x16x32_bf16(af, bfr, dacc, 0, 0, 0);
#pragma unroll
            for (int r = 0; r < 4; ++r){
                int ml = rt * 16 + kc * 4 + r;
                __hip_bfloat16 hv = f2b(softplus_f(dacc[r] + bv));
                delta[(size_t)(brow + ml) * 512 + n] = hv;
                dls[ml][n] = hv;
            }
        }
    }
    __syncthreads();

    // scan-1 carries for chunks c0, c0+1: thread handles d = tid and tid+256
    const int b = brow >> 12;
    const int c0 = (brow & 4095) >> 4;
#pragma unroll
    for (int dd = 0; dd < 2; ++dd){
        int d = dd * 256 + tid;
        float a1 = -__expf(A_log[d * 16]);
        float Av[16];
        bool fast = true;
#pragma unroll
        for (int j = 0; j < 16; ++j){
            Av[j] = -__expf(A_log[d * 16 + j]);
            fast = fast && (fabsf(Av[j] - (float)(j + 1) * a1) <= 1e-4f * fabsf(Av[j]) + 1e-7f);
        }
#pragma unroll
        for (int cc = 0; cc < 2; ++cc){
            float ap[16], ac[16];
#pragma unroll
            for (int j = 0; j < 16; ++j){ ap[j] = 1.f; ac[j] = 0.f; }
            if (fast){
                for (int t = 0; t < LC; ++t){
                    int ml = cc * 16 + t;
                    float de = b2f(dls[ml][d]);
                    float u  = de * b2f(A[(size_t)(brow + ml) * 512 + d]);
                    float p  = __expf(de * a1);
                    float q2 = p * p;
                    float q3 = q2 * p, q4 = q2 * q2;
                    float q5 = q4 * p, q6 = q4 * q2, q7 = q4 * q3, q8 = q4 * q4;
                    float qa[16] = {p, q2, q3, q4, q5, q6, q7, q8,
                                    q8 * p, q8 * q2, q8 * q3, q8 * q4, q8 * q5, q8 * q6, q8 * q7, q8 * q8};
#pragma unroll
                    for (int j = 0; j < 16; ++j){
                        ap[j] *= qa[j];
                        ac[j] = qa[j] * ac[j] + u * Bls[ml][j];
                    }
                }
            } else {
                for (int t = 0; t < LC; ++t){
                    int ml = cc * 16 + t;
                    float de = b2f(dls[ml][d]);
                    float u  = de * b2f(A[(size_t)(brow + ml) * 512 + d]);
#pragma unroll
                    for (int j = 0; j < 16; ++j){
                        float da = __expf(de * Av[j]);
                        ap[j] *= da;
                        ac[j] = da * ac[j] + u * Bls[ml][j];
                    }
                }
            }
            __hip_bfloat16 av16[16], bv16[16];
#pragma unroll
            for (int j = 0; j < 16; ++j){ av16[j] = f2b(ap[j]); bv16[j] = f2b(ac[j]); }
            size_t o = (size_t)(c0 + cc) * CSTRIDE + (size_t)(b * DIN + d) * 16;
            *(float4*)(Acar + o)     = *(const float4*)(av16);
            *(float4*)(Acar + o + 8) = *(const float4*)(av16 + 8);
            *(float4*)(Bcar + o)     = *(const float4*)(bv16);
            *(float4*)(Bcar + o + 8) = *(const float4*)(bv16 + 8);
        }
    }
}

// ---------------- causal depthwise conv k=4 + SiLU (bf16 in/out, 4-wide) ----------------
__global__ __launch_bounds__(256) void k_conv(const __hip_bfloat16* __restrict__ xz,
                                              const float* __restrict__ cw,
                                              const float* __restrict__ cb,
                                              __hip_bfloat16* __restrict__ xc){
    int idx = blockIdx.x * 256 + threadIdx.x;
    int d4 = (idx & 127) * 4;
    int bl = idx >> 7;
    int l  = bl & (LSEQ - 1);
    const __hip_bfloat16* base = xz + (size_t)bl * DXZ + d4;
    float4 bias = *(const float4*)(cb + d4);
    float acc[4] = {bias.x, bias.y, bias.z, bias.w};
    float4 w0 = *(const float4*)(cw + (d4 + 0) * 4);
    float4 w1 = *(const float4*)(cw + (d4 + 1) * 4);
    float4 w2 = *(const float4*)(cw + (d4 + 2) * 4);
    float4 w3 = *(const float4*)(cw + (d4 + 3) * 4);
    const float* wj[4] = {(const float*)&w0, (const float*)&w1, (const float*)&w2, (const float*)&w3};
#pragma unroll
    for (int t = 0; t < 4; ++t){
        int ls = l - (3 - t);
        if (ls >= 0){
            bf4 v = *(const bf4*)(base - (size_t)(3 - t) * DXZ);
#pragma unroll
            for (int j = 0; j < 4; ++j) acc[j] += wj[j][t] * b2f(v.v[j]);
        }
    }
    bf4 o;
#pragma unroll
    for (int j = 0; j < 4; ++j) o.v[j] = f2b(silu_f(acc[j]));
    *(bf4*)(xc + (size_t)bl * DIN + d4) = o;
}

// ---------------- scan pass 2: 256-chunk prefix over bf16 carries, f32 compute ----------------
__global__ __launch_bounds__(256) void k_scan2(const __hip_bfloat16* __restrict__ Acar,
                                               const __hip_bfloat16* __restrict__ Bcar,
                                               __hip_bfloat16* __restrict__ hinit){
    __shared__ float a_s[16][257];
    __shared__ float b_s[16][257];
    const int tid = threadIdx.x;
    const int idx0 = blockIdx.x * 16;
    const int cs = tid >> 4, s_ld = tid & 15;
#pragma unroll
    for (int r = 0; r < 16; ++r){
        int c = r * 16 + cs;
        size_t g = (size_t)c * CSTRIDE + idx0 + s_ld;
        a_s[s_ld][c] = b2f(Acar[g]);
        b_s[s_ld][c] = b2f(Bcar[g]);
    }
    __syncthreads();
    const int lane = tid & 63, w = tid >> 6;
#pragma unroll
    for (int i = 0; i < 4; ++i){
        int s = w * 4 + i;
        float a4[4], b4[4];
#pragma unroll
        for (int k = 0; k < 4; ++k){ a4[k] = a_s[s][4 * lane + k]; b4[k] = b_s[s][4 * lane + k]; }
        float av = a4[0], bv = b4[0];
#pragma unroll
        for (int k = 1; k < 4; ++k){ bv = a4[k] * bv + b4[k]; av *= a4[k]; }
#pragma unroll
        for (int d2 = 1; d2 < 64; d2 <<= 1){
            float ao = __shfl_up(av, d2);
            float bo = __shfl_up(bv, d2);
            if (lane >= d2){ bv = av * bo + bv; av = ao * av; }
        }
        float bx = __shfl_up(bv, 1);
        if (lane == 0) bx = 0.f;
        float h = bx;
        b_s[s][4 * lane] = h;
#pragma unroll
        for (int k = 0; k < 3; ++k){ h = a4[k] * h + b4[k]; b_s[s][4 * lane + 1 + k] = h; }
    }
    __syncthreads();
#pragma unroll
    for (int r = 0; r < 16; ++r){
        int c = r * 16 + cs;
        hinit[(size_t)c * CSTRIDE + idx0 + s_ld] = f2b(b_s[s_ld][c]);
    }
}

// ---------------- scan pass 3: replay (LC=16, staged) + fused (y + D*xc)*silu(z), coalesced y store ----------------
__global__ __launch_bounds__(512) void k_scan3(const __hip_bfloat16* __restrict__ delta,
                                               const __hip_bfloat16* __restrict__ xc,
                                               const __hip_bfloat16* __restrict__ xz,
                                               const float* __restrict__ xdbl,
                                               const float* __restrict__ A_log,
                                               const float* __restrict__ D_ssm,
                                               const __hip_bfloat16* __restrict__ hinit,
                                               __hip_bfloat16* __restrict__ y){
    int bx = blockIdx.x;
    int dh = bx & 1;
    int c  = (bx >> 1) & (NC - 1);
    int b  = bx >> 9;
    int tid = threadIdx.x;
    int dloc = tid >> 1, nh = tid & 1;
    int d = dh * 256 + dloc;
    int n0 = nh * 8;
    int rb = b * LSEQ + c * LC;
    __shared__ __align__(16) __hip_bfloat16 dl[LC][256];
    __shared__ __align__(16) __hip_bfloat16 xl[LC][256];
    __shared__ __align__(16) __hip_bfloat16 zl[LC][256];
    __shared__ float Bs[LC][DS], Cs[LC][DS];
    const int w = tid >> 6, lane = tid & 63;
    {
        size_t rowg = (size_t)(rb + 2 * w + (lane >> 5));
        int col = (lane & 31) * 8;
        gl_lds16(delta + rowg * 512 + dh * 256 + col, &dl[2 * w][0]);
        gl_lds16(xc    + rowg * 512 + dh * 256 + col, &xl[2 * w][0]);
        gl_lds16(xz    + rowg * 1024 + 512 + dh * 256 + col, &zl[2 * w][0]);
    }
    if (tid < 256){
        int t = tid >> 4, n = tid & 15;
        Bs[t][n] = xdbl[(size_t)(rb + t) * GXP + RANK + n];
    } else {
        int t = (tid >> 4) - 16, n = tid & 15;
        Cs[t][n] = xdbl[(size_t)(rb + t) * GXP + RANK + DS + n];
    }
    __syncthreads();
    float Av[8];
    float a1 = -__expf(A_log[d * 16]);
    bool fast = true;
#pragma unroll
    for (int j = 0; j < 8; ++j){
        Av[j] = -__expf(A_log[d * 16 + n0 + j]);
        fast = fast && (fabsf(Av[j] - (float)(n0 + j + 1) * a1) <= 1e-4f * fabsf(Av[j]) + 1e-7f);
    }
    float h[8];
    size_t ho = (size_t)c * CSTRIDE + (size_t)(b * DIN + d) * 16 + n0;
    {
        short8 hv = *(const short8*)(hinit + ho);
#pragma unroll
        for (int j = 0; j < 8; ++j) h[j] = b2f(((const __hip_bfloat16*)&hv)[j]);
    }
    float Dd = D_ssm[d];
    if (fast){
#pragma unroll 4
        for (int t = 0; t < LC; ++t){
            float de  = b2f(dl[t][dloc]);
            float xcv = b2f(xl[t][dloc]);
            float u = de * xcv;
            float p  = __expf(de * a1);
            float p2 = p * p, p3 = p2 * p, p4 = p2 * p2;
            float qda[8] = {p, p2, p3, p4, p4 * p, p4 * p2, p4 * p3, p4 * p4};
            float bp = nh ? qda[7] : 1.f;
#pragma unroll
            for (int j = 0; j < 8; ++j)
                h[j] = (qda[j] * bp) * h[j] + u * Bs[t][n0 + j];
            float e0 = h[0] * Cs[t][n0]     + h[1] * Cs[t][n0 + 1];
            float e1 = h[2] * Cs[t][n0 + 2] + h[3] * Cs[t][n0 + 3];
            float e2 = h[4] * Cs[t][n0 + 4] + h[5] * Cs[t][n0 + 5];
            float e3 = h[6] * Cs[t][n0 + 6] + h[7] * Cs[t][n0 + 7];
            float yv = (e0 + e1) + (e2 + e3);
            yv += __shfl_xor(yv, 1);
            if (nh == 0){
                float zv = b2f(zl[t][dloc]);
                zl[t][dloc] = f2b((yv + Dd * xcv) * silu_f(zv));
            }
        }
    } else {
        for (int t = 0; t < LC; ++t){
            float de  = b2f(dl[t][dloc]);
            float xcv = b2f(xl[t][dloc]);
            float u = de * xcv;
            float yv = 0.f;
#pragma unroll
            for (int j = 0; j < 8; ++j){
                float da = __expf(de * Av[j]);
                h[j] = da * h[j] + u * Bs[t][n0 + j];
                yv += h[j] * Cs[t][n0 + j];
            }
            yv += __shfl_xor(yv, 1);
            if (nh == 0){
                float zv = b2f(zl[t][dloc]);
                zl[t][dloc] = f2b((yv + Dd * xcv) * silu_f(zv));
            }
        }
    }
    __syncthreads();
    {
        int row = tid >> 5, colv = (tid & 31) * 8;
        *(float4*)(y + (size_t)(rb + row) * 512 + dh * 256 + colv) = *(const float4*)(&zl[row][colv]);
    }
}

extern "C" void kernel_launch(void* const* d_in, const int* in_sizes, int n_in,
                              void* d_out, int out_size, void* d_ws, size_t ws_size,
                              hipStream_t stream){
    const float* x      = (const float*)d_in[0];
    const float* ln_w   = (const float*)d_in[1];
    const float* ln_b   = (const float*)d_in[2];
    const float* W_in   = (const float*)d_in[3];
    const float* conv_w = (const float*)d_in[4];
    const float* conv_b = (const float*)d_in[5];
    const float* W_xproj= (const float*)d_in[6];
    const float* W_dt   = (const float*)d_in[7];
    const float* b_dt   = (const float*)d_in[8];
    const float* A_log  = (const float*)d_in[9];
    const float* D_ssm  = (const float*)d_in[10];
    const float* W_outp = (const float*)d_in[11];
    const float* c1_w   = (const float*)d_in[12];
    const float* c1_b   = (const float*)d_in[13];
    const float* c2_w   = (const float*)d_in[14];
    const float* c2_b   = (const float*)d_in[15];
    const float* c3_w   = (const float*)d_in[16];
    const float* c3_b   = (const float*)d_in[17];
    const float* W_out  = (const float*)d_in[18];
    const float* b_out  = (const float*)d_in[19];
    const float* W_skip = (const float*)d_in[20];
    const float* b_skip = (const float*)d_in[21];
    float* out = (float*)d_out;

    char* base = (char*)d_ws;
    const size_t MB = 1024 * 1024;
    const size_t KB = 1024;
    __hip_bfloat16* Acomb = (__hip_bfloat16*)(base);            // [8192][512]  8 MB
    __hip_bfloat16* xzb   = (__hip_bfloat16*)(base + 8*MB);     // [8192][1024] 16 MB
    __hip_bfloat16* xcb   = (__hip_bfloat16*)(base + 24*MB);    // [8192][512]  8 MB
    float*          xdbl  = (float*)        (base + 32*MB);     // [8192][48]   1.5 MB
    __hip_bfloat16* deltab= (__hip_bfloat16*)(base + 34*MB);    // [8192][512]  8 MB
    __hip_bfloat16* Acar  = (__hip_bfloat16*)(base + 42*MB);    // 8 MB (bf16, NC=256)
    __hip_bfloat16* Bcar  = (__hip_bfloat16*)(base + 50*MB);    // 8 MB
    __hip_bfloat16* hinit = (__hip_bfloat16*)(base + 58*MB);    // 8 MB
    __hip_bfloat16* Winb  = (__hip_bfloat16*)(base + 66*MB);            // 512 KB
    __hip_bfloat16* Wxpb  = (__hip_bfloat16*)(base + 66*MB + 512*KB);   // 64 KB
    __hip_bfloat16* Wopb  = (__hip_bfloat16*)(base + 66*MB + 576*KB);   // 256 KB
    __hip_bfloat16* Wcb   = (__hip_bfloat16*)(base + 66*MB + 832*KB);   // 256 KB
    __hip_bfloat16* Wdtb  = (__hip_bfloat16*)(base + 66*MB + 1088*KB);  // 32 KB
    float*          bc    = (float*)        (base + 66*MB + 1120*KB);   // 4 KB
    float*          msw   = (float*)        (base + 66*MB + 1124*KB);   // 20 KB
    __hip_bfloat16* xnb   = Acomb + 256;                        // stride 512
    __hip_bfloat16* ybf   = Bcar;                               // alias: Bcar dead after scan2 (8 MB)

    const int M = BSZ * LSEQ;   // 8192

    k_pre<<<dim3(512), dim3(256), 0, stream>>>(x, ln_w, ln_b, W_in, W_xproj, W_outp, W_out, W_skip,
                                               b_out, b_skip, W_dt, c1_w, c1_b, c2_w, c2_b, c3_w, c3_b,
                                               xnb, Winb, Wxpb, Wopb, Wcb, Wdtb, bc, msw);
    k_mgemm<8, 128, 128><<<dim3(64, 8), dim3(256), 0, stream>>>(xnb, 512, Winb, nullptr, xzb, DXZ, 1024, 256);
    k_conv<<<dim3(M * DIN / 4 / 256), dim3(256), 0, stream>>>(xzb, conv_w, conv_b, xcb);
    // xproj + dt + scan-1 carries fused
    k_xpdt<<<dim3(256), dim3(256), 0, stream>>>(xcb, Wxpb, Wdtb, b_dt, A_log, xdbl, deltab, Acar, Bcar);
    k_scan2<<<dim3(1024), dim3(256), 0, stream>>>(Acar, Bcar, hinit);
    k_scan3<<<dim3(BSZ * NC * 2), dim3(512), 0, stream>>>(deltab, xcb, xzb, xdbl, A_log, D_ssm, hinit, ybf);
    k_mgemm<32, 64, 64><<<dim3(128, 4), dim3(256), 0, stream>>>(ybf, 512, Wopb, nullptr, Acomb, 512, 256, 512,
                                                                nullptr, xnb, msw);
    k_mgemm<17, 64, 64><<<dim3(128, 4), dim3(256), 0, stream>>>(Acomb, 512, Wcb, bc, out, DM, 256, 512, x);
}

// Round 13
// 219.171 us; speedup vs baseline: 1.9504x; 1.0461x over previous
//
#include <hip/hip_runtime.h>
#include <hip/hip_bf16.h>
#include <math.h>
#include <cstddef>

#define BSZ 2
#define DM 256
#define LSEQ 4096
#define DIN 512
#define DXZ 1024
#define DS 16
#define RANK 16
#define GXP 48
#define LC 16
#define NC 256   // LSEQ / LC
#define CSTRIDE (BSZ * DIN * 16)   // 16384 sequences

typedef __attribute__((ext_vector_type(8))) short short8;
typedef __attribute__((ext_vector_type(4))) float f32x4;
struct bf4 { __hip_bfloat16 v[4]; };

__device__ __forceinline__ float silu_f(float x){ return x / (1.f + __expf(-x)); }
__device__ __forceinline__ float softplus_f(float x){ return fmaxf(x, 0.f) + log1pf(__expf(-fabsf(x))); }
__device__ __forceinline__ float b2f(__hip_bfloat16 v){ return __bfloat162float(v); }
__device__ __forceinline__ __hip_bfloat16 f2b(float v){ return __float2bfloat16(v); }

__device__ __forceinline__ void gl_lds16(const void* g, void* s){
    __builtin_amdgcn_global_load_lds((const __attribute__((address_space(1))) void*)g,
                                     (__attribute__((address_space(3))) void*)s, 16, 0, 0);
}

// ---------------- fused: LayerNorm-transpose (blocks 0-255) + weight cvt/pack (blocks 256-511) ----------------
__global__ __launch_bounds__(256) void k_pre(const float* __restrict__ x,
                                             const float* __restrict__ lnw, const float* __restrict__ lnb,
                                             const float* __restrict__ W_in, const float* __restrict__ W_xproj,
                                             const float* __restrict__ W_outp, const float* __restrict__ W_out,
                                             const float* __restrict__ W_skip, const float* __restrict__ b_out,
                                             const float* __restrict__ b_skip, const float* __restrict__ W_dt,
                                             const float* __restrict__ c1w, const float* __restrict__ c1b,
                                             const float* __restrict__ c2w, const float* __restrict__ c2b,
                                             const float* __restrict__ c3w, const float* __restrict__ c3b,
                                             __hip_bfloat16* __restrict__ xnb,
                                             __hip_bfloat16* __restrict__ Winb, __hip_bfloat16* __restrict__ Wxpb,
                                             __hip_bfloat16* __restrict__ Wopb, __hip_bfloat16* __restrict__ Wcb,
                                             __hip_bfloat16* __restrict__ Wdtb, float* __restrict__ bc,
                                             float* __restrict__ msw){
    __shared__ float tile[DM * 33];
    __shared__ float rsum[8][32], rsq[8][32];
    __shared__ float mu_s[32], rs_s[32];
    int tid = threadIdx.x;
    if (blockIdx.x < 256){
        int b  = blockIdx.x >> 7;
        int l0 = (blockIdx.x & 127) << 5;
        const float* xb = x + (size_t)b * DM * LSEQ;
        int lls = tid & 31, chi = tid >> 5;
        for (int cc = 0; cc < 32; ++cc){
            int c = cc * 8 + chi;
            tile[c * 33 + lls] = xb[(size_t)c * LSEQ + l0 + lls];
        }
        __syncthreads();
        int part = tid >> 5, l = tid & 31;
        float s = 0.f, sq = 0.f;
        for (int i = 0; i < 32; ++i){
            float v = tile[(part * 32 + i) * 33 + l];
            s += v; sq += v * v;
        }
        rsum[part][l] = s; rsq[part][l] = sq;
        __syncthreads();
        if (tid < 32){
            float ts = 0.f, tq = 0.f;
            for (int p = 0; p < 8; ++p){ ts += rsum[p][tid]; tq += rsq[p][tid]; }
            float mu  = ts * (1.f / DM);
            float var = tq * (1.f / DM) - mu * mu;
            mu_s[tid] = mu;
            rs_s[tid] = rsqrtf(var + 1e-5f);
        }
        __syncthreads();
        int c0 = tid & 63, lh = tid >> 6;
        for (int i = 0; i < 8; ++i){
            int ll = lh + 4 * i;
            float mu = mu_s[ll], rs = rs_s[ll];
            __hip_bfloat16* orow = xnb + (size_t)(b * LSEQ + l0 + ll) * 512;
            for (int j = 0; j < 4; ++j){
                int c = c0 + 64 * j;
                orow[c] = f2b((tile[c * 33 + ll] - mu) * rs * lnw[c] + lnb[c]);
            }
        }
    } else {
        int i0 = (blockIdx.x - 256) * 256 + tid;
        const int T = 256 * 256;
        for (int j = i0; j < 1024 * 256; j += T) Winb[j] = f2b(W_in[j]);
        for (int j = i0; j < 64 * 512; j += T){
            int r = j >> 9;
            Wxpb[j] = f2b(r < GXP ? W_xproj[r * 512 + (j & 511)] : 0.f);
        }
        for (int j = i0; j < 256 * 512; j += T) Wopb[j] = f2b(W_outp[j]);
        for (int j = i0; j < 256 * 512; j += T){
            int n = j >> 9, k = j & 511;
            Wcb[j] = f2b(k < 256 ? W_out[n * 256 + k] : W_skip[n * 256 + (k - 256)]);
        }
        for (int j = i0; j < 512 * 32; j += T){
            int n = j >> 5, k = j & 31;
            Wdtb[j] = f2b(k < 16 ? W_dt[n * 16 + k] : 0.f);
        }
        if (i0 < 256){
            bc[i0] = b_out[i0] + b_skip[i0];
            float* m = msw + i0 * 20;
            m[0] = c1w[i0*3]; m[1] = c1w[i0*3+1]; m[2] = c1w[i0*3+2];
            for (int j = 0; j < 5; ++j) m[3+j] = c2w[i0*5+j];
            for (int j = 0; j < 7; ++j) m[8+j] = c3w[i0*7+j];
            m[15] = c1b[i0]; m[16] = c2b[i0]; m[17] = c3b[i0];
            m[18] = 0.f; m[19] = 0.f;
        }
    }
}

// ---------------- bf16 MFMA GEMM: C[M][ldc] = A[M][lda-strided] @ W[N][K]^T ----------------
// EPI: 1 = +bias, 8 = bf16 out, 16 = fused transpose+residual (xres), 32 = fused msconv epilogue
template<int EPI, int BM = 128, int BN = 64>
__global__ __launch_bounds__(256) void k_mgemm(const __hip_bfloat16* __restrict__ A, int lda,
                                               const __hip_bfloat16* __restrict__ W,
                                               const float* __restrict__ bias,
                                               void* __restrict__ Cv, int ldc,
                                               int N, int K,
                                               const float* __restrict__ xres = nullptr,
                                               const __hip_bfloat16* __restrict__ xnb2 = nullptr,
                                               const float* __restrict__ msw = nullptr){
    constexpr int SA  = BM / 8;
    constexpr int SAW = SA / 4;
    constexpr int SB  = BN / 8;
    constexpr int SBW = SB / 4;
    constexpr int WROWS = BM / 2;
    constexpr int WCOLS = BN / 2;
    constexpr int MI = WROWS / 16;
    constexpr int NI = WCOLS / 16;
    __shared__ __align__(16) __hip_bfloat16 As[BM * 64];
    __shared__ __align__(16) __hip_bfloat16 Ws[BN * 64];
    __shared__ float tileT[(EPI & 16) ? 64 * 65 : 1];
    const int tid = threadIdx.x;
    const int wave = tid >> 6, lane = tid & 63;
    const int brow = blockIdx.x * BM, bcol = blockIdx.y * BN;
    const int wm = wave >> 1, wn = wave & 1;

    const int a_row = lane >> 3;
    const int a_chk = lane & 7;
    const int a_scol = ((a_chk ^ a_row) * 8);

    const int lrow = lane & 15;
    const int kc = lane >> 4;
    const int r7 = lrow & 7;

    f32x4 acc[MI][NI] = {};

    for (int k0 = 0; k0 < K; k0 += 64){
#pragma unroll
        for (int j = 0; j < SAW; ++j){
            int seg = wave * SAW + j;
            const __hip_bfloat16* src = A + (size_t)(brow + seg * 8 + a_row) * lda + k0 + a_scol;
            gl_lds16(src, &As[seg * 512]);
        }
#pragma unroll
        for (int j = 0; j < SBW; ++j){
            int seg = wave * SBW + j;
            const __hip_bfloat16* src = W + (size_t)(bcol + seg * 8 + a_row) * K + k0 + a_scol;
            gl_lds16(src, &Ws[seg * 512]);
        }
        __syncthreads();
#pragma unroll
        for (int kk = 0; kk < 2; ++kk){
            int kchunk = kk * 4 + kc;
            short8 af[MI], bfr[NI];
#pragma unroll
            for (int mi = 0; mi < MI; ++mi){
                int row = wm * WROWS + mi * 16 + lrow;
                af[mi] = *(const short8*)&As[row * 64 + ((kchunk ^ r7) * 8)];
            }
#pragma unroll
            for (int ni = 0; ni < NI; ++ni){
                int row = wn * WCOLS + ni * 16 + lrow;
                bfr[ni] = *(const short8*)&Ws[row * 64 + ((kchunk ^ r7) * 8)];
            }
#pragma unroll
            for (int mi = 0; mi < MI; ++mi)
#pragma unroll
                for (int ni = 0; ni < NI; ++ni)
                    acc[mi][ni] = __builtin_amdgcn_mfma_f32_16x16x32_bf16(af[mi], bfr[ni], acc[mi][ni], 0, 0, 0);
        }
        __syncthreads();
    }

    if (EPI & 16){
#pragma unroll
        for (int ni = 0; ni < NI; ++ni){
            int nl = wn * WCOLS + ni * 16 + lrow;
#pragma unroll
            for (int mi = 0; mi < MI; ++mi){
                int ml = wm * WROWS + mi * 16 + kc * 4;
#pragma unroll
                for (int r = 0; r < 4; ++r)
                    tileT[nl * 65 + ml + r] = acc[mi][ni][r];
            }
        }
        __syncthreads();
        int b = brow >> 12, l0 = brow & 4095;
        int lr = tid & 63, nr = tid >> 6;
        float* out = (float*)Cv;
#pragma unroll
        for (int rr = 0; rr < 16; ++rr){
            int n = rr * 4 + nr;
            size_t o = (size_t)(b * DM + bcol + n) * LSEQ + l0 + lr;
            out[o] = tileT[n * 65 + lr] + bias[bcol + n] + xres[o];
        }
        return;
    }

    if (EPI & 32){
#pragma unroll
        for (int ni = 0; ni < NI; ++ni){
            int n = bcol + wn * WCOLS + ni * 16 + lrow;
            float4 wv0 = *(const float4*)&msw[n * 20];
            float4 wv1 = *(const float4*)&msw[n * 20 + 4];
            float4 wv2 = *(const float4*)&msw[n * 20 + 8];
            float4 wv3 = *(const float4*)&msw[n * 20 + 12];
            float4 wv4 = *(const float4*)&msw[n * 20 + 16];
#pragma unroll
            for (int mi = 0; mi < MI; ++mi){
                int m0 = brow + wm * WROWS + mi * 16 + kc * 4;
                int l  = m0 & (LSEQ - 1);
                int bL = m0 - l;
                float v[10];
#pragma unroll
                for (int k = 0; k < 10; ++k){
                    int ll = l - 3 + k;
                    v[k] = ((unsigned)ll < LSEQ) ? b2f(xnb2[(size_t)(bL + ll) * 512 + n]) : 0.f;
                }
#pragma unroll
                for (int r = 0; r < 4; ++r){
                    float a1 = wv3.w + wv0.x * v[r+2] + wv0.y * v[r+3] + wv0.z * v[r+4];
                    float a2 = wv4.x + wv0.w * v[r+1] + wv1.x * v[r+2] + wv1.y * v[r+3]
                                     + wv1.z * v[r+4] + wv1.w * v[r+5];
                    float a3 = wv4.y + wv2.x * v[r] + wv2.y * v[r+1] + wv2.z * v[r+2]
                                     + wv2.w * v[r+3] + wv3.x * v[r+4] + wv3.y * v[r+5]
                                     + wv3.z * v[r+6];
                    float res = acc[mi][ni][r] + silu_f(a1) + silu_f(a2) + silu_f(a3);
                    ((__hip_bfloat16*)Cv)[(size_t)(m0 + r) * ldc + n] = f2b(res);
                }
            }
        }
        return;
    }

#pragma unroll
    for (int ni = 0; ni < NI; ++ni){
        int n = bcol + wn * WCOLS + ni * 16 + lrow;
        if (n >= N) continue;
        float bv = (EPI & 1) ? bias[n] : 0.f;
#pragma unroll
        for (int mi = 0; mi < MI; ++mi){
            int m0 = brow + wm * WROWS + mi * 16 + kc * 4;
#pragma unroll
            for (int r = 0; r < 4; ++r){
                float v = acc[mi][ni][r] + bv;
                if (EPI & 8) ((__hip_bfloat16*)Cv)[(size_t)(m0 + r) * ldc + n] = f2b(v);
                else         ((float*)Cv)[(size_t)(m0 + r) * ldc + n] = v;
            }
        }
    }
}

// ---------------- fused xproj GEMM + dt GEMM + softplus + scan-1 carries (512 thr / 8 waves) ----------------
// Block handles rows brow..brow+31 = chunks c0, c0+1 (LC=16). Waves 0-3: MFMA; all 8: dt + carry tail.
__global__ __launch_bounds__(512) void k_xpdt(const __hip_bfloat16* __restrict__ A,    // xcb
                                              const __hip_bfloat16* __restrict__ Wxp,
                                              const __hip_bfloat16* __restrict__ Wdt,
                                              const float* __restrict__ bdt,
                                              const float* __restrict__ A_log,
                                              float* __restrict__ xdbl,
                                              __hip_bfloat16* __restrict__ delta,
                                              __hip_bfloat16* __restrict__ Acar,
                                              __hip_bfloat16* __restrict__ Bcar){
    __shared__ __align__(16) __hip_bfloat16 As[32 * 64];
    __shared__ __align__(16) __hip_bfloat16 Ws[64 * 64];
    __shared__ __hip_bfloat16 xdl[32][34];
    __shared__ __hip_bfloat16 dls[32][520];   // delta staged (pad 8 -> 2-way banks)
    __shared__ float Bls[32][16];             // B columns staged
    const int tid = threadIdx.x, wave = tid >> 6, lane = tid & 63;
    const int brow = blockIdx.x * 32;
    const int wm = (wave >> 1) & 1, wn = wave & 1;
    const int a_row = lane >> 3, a_chk = lane & 7, a_scol = ((a_chk ^ a_row) * 8);
    const int lrow = lane & 15, kc = lane >> 4, r7 = lrow & 7;

    for (int i = tid; i < 32 * 18; i += 512){
        int rr = i / 18, cc = 16 + i % 18;
        xdl[rr][cc] = f2b(0.f);
    }

    f32x4 acc[2] = {};
    for (int k0 = 0; k0 < 512; k0 += 64){
        if (wave < 4){
            int seg = wave;
            gl_lds16(A + (size_t)(brow + seg * 8 + a_row) * 512 + k0 + a_scol, &As[seg * 512]);
        }
        {
            int seg = wave;   // 8 waves stage the 8 W segments
            gl_lds16(Wxp + (size_t)(seg * 8 + a_row) * 512 + k0 + a_scol, &Ws[seg * 512]);
        }
        __syncthreads();
        if (wave < 4){
#pragma unroll
            for (int kk = 0; kk < 2; ++kk){
                int kchunk = kk * 4 + kc;
                short8 af = *(const short8*)&As[(wm * 16 + lrow) * 64 + ((kchunk ^ r7) * 8)];
#pragma unroll
                for (int ni = 0; ni < 2; ++ni){
                    short8 bfr = *(const short8*)&Ws[(wn * 32 + ni * 16 + lrow) * 64 + ((kchunk ^ r7) * 8)];
                    acc[ni] = __builtin_amdgcn_mfma_f32_16x16x32_bf16(af, bfr, acc[ni], 0, 0, 0);
                }
            }
        }
        __syncthreads();
    }

    // write xdbl (f32, n<48); stage dt-inputs (n<16) and B (16<=n<32) to LDS
    if (wave < 4){
#pragma unroll
        for (int ni = 0; ni < 2; ++ni){
            int n = wn * 32 + ni * 16 + lrow;
            if (n < 48){
#pragma unroll
                for (int r = 0; r < 4; ++r){
                    int ml = wm * 16 + kc * 4 + r;
                    float fv = acc[ni][r];
                    xdbl[(size_t)(brow + ml) * 48 + n] = fv;
                    if (n < 16) xdl[ml][n] = f2b(fv);
                    else if (n < 32) Bls[ml][n - 16] = fv;
                }
            }
        }
    }
    __syncthreads();

    // dt: delta = softplus(xdl @ Wdt^T + bdt); 8 waves x 4 col-tiles
#pragma unroll
    for (int ct4 = 0; ct4 < 4; ++ct4){
        int ct = wave * 4 + ct4;
        int n = ct * 16 + lrow;
        short8 bfr = *(const short8*)&Wdt[(size_t)n * 32 + kc * 8];
        float bv = bdt[n];
#pragma unroll
        for (int rt = 0; rt < 2; ++rt){
            short8 af = *(const short8*)&xdl[rt * 16 + lrow][kc * 8];
            f32x4 dacc = {};
            dacc = __builtin_amdgcn_mfma_f32_16x16x32_bf16(af, bfr, dacc, 0, 0, 0);
#pragma unroll
            for (int r = 0; r < 4; ++r){
                int ml = rt * 16 + kc * 4 + r;
                __hip_bfloat16 hv = f2b(softplus_f(dacc[r] + bv));
                delta[(size_t)(brow + ml) * 512 + n] = hv;
                dls[ml][n] = hv;
            }
        }
    }
    __syncthreads();

    // scan-1 carries for chunks c0, c0+1: one d per thread (512 threads = 512 channels)
    const int b = brow >> 12;
    const int c0 = (brow & 4095) >> 4;
    {
        const int d = tid;
        float a1 = -__expf(A_log[d * 16]);
        float Av[16];
        bool fast = true;
#pragma unroll
        for (int j = 0; j < 16; ++j){
            Av[j] = -__expf(A_log[d * 16 + j]);
            fast = fast && (fabsf(Av[j] - (float)(j + 1) * a1) <= 1e-4f * fabsf(Av[j]) + 1e-7f);
        }
#pragma unroll
        for (int cc = 0; cc < 2; ++cc){
            float ap[16], ac[16];
#pragma unroll
            for (int j = 0; j < 16; ++j){ ap[j] = 1.f; ac[j] = 0.f; }
            if (fast){
                for (int t = 0; t < LC; ++t){
                    int ml = cc * 16 + t;
                    float de = b2f(dls[ml][d]);
                    float u  = de * b2f(A[(size_t)(brow + ml) * 512 + d]);
                    float p  = __expf(de * a1);
                    float q2 = p * p;
                    float q3 = q2 * p, q4 = q2 * q2;
                    float q5 = q4 * p, q6 = q4 * q2, q7 = q4 * q3, q8 = q4 * q4;
                    float qa[16] = {p, q2, q3, q4, q5, q6, q7, q8,
                                    q8 * p, q8 * q2, q8 * q3, q8 * q4, q8 * q5, q8 * q6, q8 * q7, q8 * q8};
#pragma unroll
                    for (int j = 0; j < 16; ++j){
                        ap[j] *= qa[j];
                        ac[j] = qa[j] * ac[j] + u * Bls[ml][j];
                    }
                }
            } else {
                for (int t = 0; t < LC; ++t){
                    int ml = cc * 16 + t;
                    float de = b2f(dls[ml][d]);
                    float u  = de * b2f(A[(size_t)(brow + ml) * 512 + d]);
#pragma unroll
                    for (int j = 0; j < 16; ++j){
                        float da = __expf(de * Av[j]);
                        ap[j] *= da;
                        ac[j] = da * ac[j] + u * Bls[ml][j];
                    }
                }
            }
            __hip_bfloat16 av16[16], bv16[16];
#pragma unroll
            for (int j = 0; j < 16; ++j){ av16[j] = f2b(ap[j]); bv16[j] = f2b(ac[j]); }
            size_t o = (size_t)(c0 + cc) * CSTRIDE + (size_t)(b * DIN + d) * 16;
            *(float4*)(Acar + o)     = *(const float4*)(av16);
            *(float4*)(Acar + o + 8) = *(const float4*)(av16 + 8);
            *(float4*)(Bcar + o)     = *(const float4*)(bv16);
            *(float4*)(Bcar + o + 8) = *(const float4*)(bv16 + 8);
        }
    }
}

// ---------------- causal depthwise conv k=4 + SiLU (bf16 in/out, 4-wide) ----------------
__global__ __launch_bounds__(256) void k_conv(const __hip_bfloat16* __restrict__ xz,
                                              const float* __restrict__ cw,
                                              const float* __restrict__ cb,
                                              __hip_bfloat16* __restrict__ xc){
    int idx = blockIdx.x * 256 + threadIdx.x;
    int d4 = (idx & 127) * 4;
    int bl = idx >> 7;
    int l  = bl & (LSEQ - 1);
    const __hip_bfloat16* base = xz + (size_t)bl * DXZ + d4;
    float4 bias = *(const float4*)(cb + d4);
    float acc[4] = {bias.x, bias.y, bias.z, bias.w};
    float4 w0 = *(const float4*)(cw + (d4 + 0) * 4);
    float4 w1 = *(const float4*)(cw + (d4 + 1) * 4);
    float4 w2 = *(const float4*)(cw + (d4 + 2) * 4);
    float4 w3 = *(const float4*)(cw + (d4 + 3) * 4);
    const float* wj[4] = {(const float*)&w0, (const float*)&w1, (const float*)&w2, (const float*)&w3};
#pragma unroll
    for (int t = 0; t < 4; ++t){
        int ls = l - (3 - t);
        if (ls >= 0){
            bf4 v = *(const bf4*)(base - (size_t)(3 - t) * DXZ);
#pragma unroll
            for (int j = 0; j < 4; ++j) acc[j] += wj[j][t] * b2f(v.v[j]);
        }
    }
    bf4 o;
#pragma unroll
    for (int j = 0; j < 4; ++j) o.v[j] = f2b(silu_f(acc[j]));
    *(bf4*)(xc + (size_t)bl * DIN + d4) = o;
}

// ---------------- scan pass 2: 256-chunk prefix over bf16 carries, f32 compute ----------------
__global__ __launch_bounds__(256) void k_scan2(const __hip_bfloat16* __restrict__ Acar,
                                               const __hip_bfloat16* __restrict__ Bcar,
                                               __hip_bfloat16* __restrict__ hinit){
    __shared__ float a_s[16][257];
    __shared__ float b_s[16][257];
    const int tid = threadIdx.x;
    const int idx0 = blockIdx.x * 16;
    const int cs = tid >> 4, s_ld = tid & 15;
#pragma unroll
    for (int r = 0; r < 16; ++r){
        int c = r * 16 + cs;
        size_t g = (size_t)c * CSTRIDE + idx0 + s_ld;
        a_s[s_ld][c] = b2f(Acar[g]);
        b_s[s_ld][c] = b2f(Bcar[g]);
    }
    __syncthreads();
    const int lane = tid & 63, w = tid >> 6;
#pragma unroll
    for (int i = 0; i < 4; ++i){
        int s = w * 4 + i;
        float a4[4], b4[4];
#pragma unroll
        for (int k = 0; k < 4; ++k){ a4[k] = a_s[s][4 * lane + k]; b4[k] = b_s[s][4 * lane + k]; }
        float av = a4[0], bv = b4[0];
#pragma unroll
        for (int k = 1; k < 4; ++k){ bv = a4[k] * bv + b4[k]; av *= a4[k]; }
#pragma unroll
        for (int d2 = 1; d2 < 64; d2 <<= 1){
            float ao = __shfl_up(av, d2);
            float bo = __shfl_up(bv, d2);
            if (lane >= d2){ bv = av * bo + bv; av = ao * av; }
        }
        float bx = __shfl_up(bv, 1);
        if (lane == 0) bx = 0.f;
        float h = bx;
        b_s[s][4 * lane] = h;
#pragma unroll
        for (int k = 0; k < 3; ++k){ h = a4[k] * h + b4[k]; b_s[s][4 * lane + 1 + k] = h; }
    }
    __syncthreads();
#pragma unroll
    for (int r = 0; r < 16; ++r){
        int c = r * 16 + cs;
        hinit[(size_t)c * CSTRIDE + idx0 + s_ld] = f2b(b_s[s_ld][c]);
    }
}

// ---------------- scan pass 3: replay (LC=16, staged) + fused (y + D*xc)*silu(z), coalesced y store ----------------
__global__ __launch_bounds__(512) void k_scan3(const __hip_bfloat16* __restrict__ delta,
                                               const __hip_bfloat16* __restrict__ xc,
                                               const __hip_bfloat16* __restrict__ xz,
                                               const float* __restrict__ xdbl,
                                               const float* __restrict__ A_log,
                                               const float* __restrict__ D_ssm,
                                               const __hip_bfloat16* __restrict__ hinit,
                                               __hip_bfloat16* __restrict__ y){
    int bx = blockIdx.x;
    int dh = bx & 1;
    int c  = (bx >> 1) & (NC - 1);
    int b  = bx >> 9;
    int tid = threadIdx.x;
    int dloc = tid >> 1, nh = tid & 1;
    int d = dh * 256 + dloc;
    int n0 = nh * 8;
    int rb = b * LSEQ + c * LC;
    __shared__ __align__(16) __hip_bfloat16 dl[LC][256];
    __shared__ __align__(16) __hip_bfloat16 xl[LC][256];
    __shared__ __align__(16) __hip_bfloat16 zl[LC][256];
    __shared__ float Bs[LC][DS], Cs[LC][DS];
    const int w = tid >> 6, lane = tid & 63;
    {
        size_t rowg = (size_t)(rb + 2 * w + (lane >> 5));
        int col = (lane & 31) * 8;
        gl_lds16(delta + rowg * 512 + dh * 256 + col, &dl[2 * w][0]);
        gl_lds16(xc    + rowg * 512 + dh * 256 + col, &xl[2 * w][0]);
        gl_lds16(xz    + rowg * 1024 + 512 + dh * 256 + col, &zl[2 * w][0]);
    }
    if (tid < 256){
        int t = tid >> 4, n = tid & 15;
        Bs[t][n] = xdbl[(size_t)(rb + t) * GXP + RANK + n];
    } else {
        int t = (tid >> 4) - 16, n = tid & 15;
        Cs[t][n] = xdbl[(size_t)(rb + t) * GXP + RANK + DS + n];
    }
    __syncthreads();
    float Av[8];
    float a1 = -__expf(A_log[d * 16]);
    bool fast = true;
#pragma unroll
    for (int j = 0; j < 8; ++j){
        Av[j] = -__expf(A_log[d * 16 + n0 + j]);
        fast = fast && (fabsf(Av[j] - (float)(n0 + j + 1) * a1) <= 1e-4f * fabsf(Av[j]) + 1e-7f);
    }
    float h[8];
    size_t ho = (size_t)c * CSTRIDE + (size_t)(b * DIN + d) * 16 + n0;
    {
        short8 hv = *(const short8*)(hinit + ho);
#pragma unroll
        for (int j = 0; j < 8; ++j) h[j] = b2f(((const __hip_bfloat16*)&hv)[j]);
    }
    float Dd = D_ssm[d];
    if (fast){
#pragma unroll 4
        for (int t = 0; t < LC; ++t){
            float de  = b2f(dl[t][dloc]);
            float xcv = b2f(xl[t][dloc]);
            float u = de * xcv;
            float p  = __expf(de * a1);
            float p2 = p * p, p3 = p2 * p, p4 = p2 * p2;
            float qda[8] = {p, p2, p3, p4, p4 * p, p4 * p2, p4 * p3, p4 * p4};
            float bp = nh ? qda[7] : 1.f;
#pragma unroll
            for (int j = 0; j < 8; ++j)
                h[j] = (qda[j] * bp) * h[j] + u * Bs[t][n0 + j];
            float e0 = h[0] * Cs[t][n0]     + h[1] * Cs[t][n0 + 1];
            float e1 = h[2] * Cs[t][n0 + 2] + h[3] * Cs[t][n0 + 3];
            float e2 = h[4] * Cs[t][n0 + 4] + h[5] * Cs[t][n0 + 5];
            float e3 = h[6] * Cs[t][n0 + 6] + h[7] * Cs[t][n0 + 7];
            float yv = (e0 + e1) + (e2 + e3);
            yv += __shfl_xor(yv, 1);
            if (nh == 0){
                float zv = b2f(zl[t][dloc]);
                zl[t][dloc] = f2b((yv + Dd * xcv) * silu_f(zv));
            }
        }
    } else {
        for (int t = 0; t < LC; ++t){
            float de  = b2f(dl[t][dloc]);
            float xcv = b2f(xl[t][dloc]);
            float u = de * xcv;
            float yv = 0.f;
#pragma unroll
            for (int j = 0; j < 8; ++j){
                float da = __expf(de * Av[j]);
                h[j] = da * h[j] + u * Bs[t][n0 + j];
                yv += h[j] * Cs[t][n0 + j];
            }
            yv += __shfl_xor(yv, 1);
            if (nh == 0){
                float zv = b2f(zl[t][dloc]);
                zl[t][dloc] = f2b((yv + Dd * xcv) * silu_f(zv));
            }
        }
    }
    __syncthreads();
    {
        int row = tid >> 5, colv = (tid & 31) * 8;
        *(float4*)(y + (size_t)(rb + row) * 512 + dh * 256 + colv) = *(const float4*)(&zl[row][colv]);
    }
}

extern "C" void kernel_launch(void* const* d_in, const int* in_sizes, int n_in,
                              void* d_out, int out_size, void* d_ws, size_t ws_size,
                              hipStream_t stream){
    const float* x      = (const float*)d_in[0];
    const float* ln_w   = (const float*)d_in[1];
    const float* ln_b   = (const float*)d_in[2];
    const float* W_in   = (const float*)d_in[3];
    const float* conv_w = (const float*)d_in[4];
    const float* conv_b = (const float*)d_in[5];
    const float* W_xproj= (const float*)d_in[6];
    const float* W_dt   = (const float*)d_in[7];
    const float* b_dt   = (const float*)d_in[8];
    const float* A_log  = (const float*)d_in[9];
    const float* D_ssm  = (const float*)d_in[10];
    const float* W_outp = (const float*)d_in[11];
    const float* c1_w   = (const float*)d_in[12];
    const float* c1_b   = (const float*)d_in[13];
    const float* c2_w   = (const float*)d_in[14];
    const float* c2_b   = (const float*)d_in[15];
    const float* c3_w   = (const float*)d_in[16];
    const float* c3_b   = (const float*)d_in[17];
    const float* W_out  = (const float*)d_in[18];
    const float* b_out  = (const float*)d_in[19];
    const float* W_skip = (const float*)d_in[20];
    const float* b_skip = (const float*)d_in[21];
    float* out = (float*)d_out;

    char* base = (char*)d_ws;
    const size_t MB = 1024 * 1024;
    const size_t KB = 1024;
    __hip_bfloat16* Acomb = (__hip_bfloat16*)(base);            // [8192][512]  8 MB
    __hip_bfloat16* xzb   = (__hip_bfloat16*)(base + 8*MB);     // [8192][1024] 16 MB
    __hip_bfloat16* xcb   = (__hip_bfloat16*)(base + 24*MB);    // [8192][512]  8 MB
    float*          xdbl  = (float*)        (base + 32*MB);     // [8192][48]   1.5 MB
    __hip_bfloat16* deltab= (__hip_bfloat16*)(base + 34*MB);    // [8192][512]  8 MB
    __hip_bfloat16* Acar  = (__hip_bfloat16*)(base + 42*MB);    // 8 MB (bf16, NC=256)
    __hip_bfloat16* Bcar  = (__hip_bfloat16*)(base + 50*MB);    // 8 MB
    __hip_bfloat16* hinit = (__hip_bfloat16*)(base + 58*MB);    // 8 MB
    __hip_bfloat16* Winb  = (__hip_bfloat16*)(base + 66*MB);            // 512 KB
    __hip_bfloat16* Wxpb  = (__hip_bfloat16*)(base + 66*MB + 512*KB);   // 64 KB
    __hip_bfloat16* Wopb  = (__hip_bfloat16*)(base + 66*MB + 576*KB);   // 256 KB
    __hip_bfloat16* Wcb   = (__hip_bfloat16*)(base + 66*MB + 832*KB);   // 256 KB
    __hip_bfloat16* Wdtb  = (__hip_bfloat16*)(base + 66*MB + 1088*KB);  // 32 KB
    float*          bc    = (float*)        (base + 66*MB + 1120*KB);   // 4 KB
    float*          msw   = (float*)        (base + 66*MB + 1124*KB);   // 20 KB
    __hip_bfloat16* xnb   = Acomb + 256;                        // stride 512
    __hip_bfloat16* ybf   = Bcar;                               // alias: Bcar dead after scan2 (8 MB)

    const int M = BSZ * LSEQ;   // 8192

    k_pre<<<dim3(512), dim3(256), 0, stream>>>(x, ln_w, ln_b, W_in, W_xproj, W_outp, W_out, W_skip,
                                               b_out, b_skip, W_dt, c1_w, c1_b, c2_w, c2_b, c3_w, c3_b,
                                               xnb, Winb, Wxpb, Wopb, Wcb, Wdtb, bc, msw);
    k_mgemm<8, 128, 128><<<dim3(64, 8), dim3(256), 0, stream>>>(xnb, 512, Winb, nullptr, xzb, DXZ, 1024, 256);
    k_conv<<<dim3(M * DIN / 4 / 256), dim3(256), 0, stream>>>(xzb, conv_w, conv_b, xcb);
    // xproj + dt + scan-1 carries fused (512 thr)
    k_xpdt<<<dim3(256), dim3(512), 0, stream>>>(xcb, Wxpb, Wdtb, b_dt, A_log, xdbl, deltab, Acar, Bcar);
    k_scan2<<<dim3(1024), dim3(256), 0, stream>>>(Acar, Bcar, hinit);
    k_scan3<<<dim3(BSZ * NC * 2), dim3(512), 0, stream>>>(deltab, xcb, xzb, xdbl, A_log, D_ssm, hinit, ybf);
    k_mgemm<32, 64, 64><<<dim3(128, 4), dim3(256), 0, stream>>>(ybf, 512, Wopb, nullptr, Acomb, 512, 256, 512,
                                                                nullptr, xnb, msw);
    k_mgemm<17, 64, 64><<<dim3(128, 4), dim3(256), 0, stream>>>(Acomb, 512, Wcb, bc, out, DM, 256, 512, x);
}